// Round 1
// baseline (778.490 us; speedup 1.0000x reference)
//
#include <hip/hip_runtime.h>

#define Bq   32
#define Cq   64
#define NPq  192
#define NOq  72
#define HDq  64
#define REGD 76
#define OUTD 79

// ---------------------------------------------------------------------------
// Kernel 1: per-(b,n) block.  Bilinear sample 72x64 gated activations -> LDS,
// 64x64 fp32 GEMM vs lsgi_w[s] (register-tiled), relu, pair-max over o,
// mean over 36 -> accumulate into sumFeat[b,n,c].
// ---------------------------------------------------------------------------
__global__ __launch_bounds__(256) void sample_gemm_kernel(
    const float* __restrict__ feat, const int H, const int W,
    const float* __restrict__ xsrc, const int xs_bstride,
    const float* __restrict__ lsgi,   // [64*64] this stage
    const float* __restrict__ lw,     // [72]
    float* __restrict__ sumFeat,      // [B*NP, 64]
    const int accumulate)
{
    __shared__ __align__(16) float sW[64 * 64];
    __shared__ __align__(16) float sPin[NOq * 64];   // reused as GEMM output
    __shared__ float sRed[4 * 64];
    __shared__ float sGate[NOq];
    __shared__ float sWx[NOq], sWy[NOq];
    __shared__ int   sIx0[NOq], sIx1[NOq], sIy0[NOq], sIy1[NOq];

    const int tid = threadIdx.x;
    const int bb  = blockIdx.x / NPq;
    const int nn  = blockIdx.x % NPq;

    // stage weight matrix into LDS (row-major [k][d])
    #pragma unroll
    for (int i = 0; i < 16; ++i) sW[tid + i * 256] = lsgi[tid + i * 256];

    // per-o bilinear setup + gate
    if (tid < NOq) {
        const int o = tid;
        const float xsv = xsrc[bb * xs_bstride + nn * NOq + o];
        const float ix  = xsv * (float)(W - 1);
        const float ys  = 1.0f - (float)o * (1.0f / (float)(NOq - 1));
        const float iy  = ys * (float)(H - 1);
        const float ix0f = floorf(ix), iy0f = floorf(iy);
        sWx[o] = ix - ix0f;
        sWy[o] = iy - iy0f;
        int ix0 = (int)ix0f; ix0 = ix0 < 0 ? 0 : (ix0 > W - 1 ? W - 1 : ix0);
        int iy0 = (int)iy0f; iy0 = iy0 < 0 ? 0 : (iy0 > H - 1 ? H - 1 : iy0);
        sIx0[o] = ix0;
        sIx1[o] = (ix0 + 1 > W - 1) ? W - 1 : ix0 + 1;
        sIy0[o] = iy0;
        sIy1[o] = (iy0 + 1 > H - 1) ? H - 1 : iy0 + 1;
        sGate[o] = 1.0f / (1.0f + __expf(-lw[o]));
    }
    __syncthreads();

    // sample: pin[o][c] = bilinear(feat[b,c], ix(o), iy(o)) * gate[o]
    const float* fb = feat + (size_t)(bb * Cq) * (size_t)(H * W);
    #pragma unroll
    for (int i = 0; i < 18; ++i) {
        const int idx = tid + i * 256;
        const int o = idx >> 6;
        const int c = idx & 63;
        const float* f = fb + c * (H * W);
        const float wx = sWx[o], wy = sWy[o];
        const int iy0W = sIy0[o] * W, iy1W = sIy1[o] * W;
        const int ix0 = sIx0[o], ix1 = sIx1[o];
        const float v00 = f[iy0W + ix0], v01 = f[iy0W + ix1];
        const float v10 = f[iy1W + ix0], v11 = f[iy1W + ix1];
        const float top = v00 + (v01 - v00) * wx;
        const float bot = v10 + (v11 - v10) * wx;
        const float v = top + (bot - top) * wy;
        sPin[idx] = v * sGate[o];
    }
    __syncthreads();

    // GEMM: out[o][d] = relu(sum_k pin[o][k] * W[k][d])
    // thread tile: 9 o-rows x 2 d-cols (d = tc, tc+32)
    const int tc = tid & 31;
    const int to = tid >> 5;
    const int o0 = to * 9;
    float acc[9][2];
    #pragma unroll
    for (int r = 0; r < 9; ++r) { acc[r][0] = 0.f; acc[r][1] = 0.f; }

    #pragma unroll
    for (int k4 = 0; k4 < 16; ++k4) {
        float wa[4], wb[4];
        #pragma unroll
        for (int j = 0; j < 4; ++j) {
            wa[j] = sW[(k4 * 4 + j) * 64 + tc];
            wb[j] = sW[(k4 * 4 + j) * 64 + tc + 32];
        }
        #pragma unroll
        for (int r = 0; r < 9; ++r) {
            const float4 p = *(const float4*)&sPin[(o0 + r) * 64 + k4 * 4];
            acc[r][0] += p.x * wa[0] + p.y * wa[1] + p.z * wa[2] + p.w * wa[3];
            acc[r][1] += p.x * wb[0] + p.y * wb[1] + p.z * wb[2] + p.w * wb[3];
        }
    }
    __syncthreads();          // everyone done reading sPin
    #pragma unroll
    for (int r = 0; r < 9; ++r) {
        sPin[(o0 + r) * 64 + tc]      = fmaxf(acc[r][0], 0.f);
        sPin[(o0 + r) * 64 + tc + 32] = fmaxf(acc[r][1], 0.f);
    }
    __syncthreads();

    // pair-max over o, partial sums over o2 (4 groups x 9 each)
    {
        const int c = tid & 63;
        const int g = tid >> 6;
        float s = 0.f;
        #pragma unroll
        for (int j = 0; j < 9; ++j) {
            const int o2 = g + 4 * j;
            s += fmaxf(sPin[(2 * o2) * 64 + c], sPin[(2 * o2 + 1) * 64 + c]);
        }
        sRed[g * 64 + c] = s;
    }
    __syncthreads();
    if (tid < 64) {
        float tot = (sRed[tid] + sRed[64 + tid] + sRed[128 + tid] + sRed[192 + tid])
                    * (1.0f / 36.0f);
        float* dst = sumFeat + (size_t)blockIdx.x * 64 + tid;
        if (accumulate) tot += *dst;
        *dst = tot;
    }
}

// ---------------------------------------------------------------------------
// Kernel 2: heads.  4 points per block (1 wave each).
// fused = sumFeat/(s+1); fc = relu(fused@fc_w+b); cls/reg/loc 2-layer MLPs;
// writes out[s] row (79 cols) and next-stage xs = sigmoid(reg[4:]).
// ---------------------------------------------------------------------------
__global__ __launch_bounds__(256) void head_kernel(
    const float* __restrict__ sumFeat, const float invS,
    const float* __restrict__ fc_w,  const float* __restrict__ fc_b,
    const float* __restrict__ cls_w, const float* __restrict__ cls_b,
    const float* __restrict__ cls_ow, const float* __restrict__ cls_ob,
    const float* __restrict__ reg_w, const float* __restrict__ reg_b,
    const float* __restrict__ reg_ow, const float* __restrict__ reg_ob,
    const float* __restrict__ loc_w, const float* __restrict__ loc_b,
    const float* __restrict__ loc_ow, const float* __restrict__ loc_ob,
    float* __restrict__ out,      // stage slab base
    float* __restrict__ xs_next)  // [B*NP, 72]
{
    const int w    = threadIdx.x >> 6;
    const int lane = threadIdx.x & 63;
    const int p    = blockIdx.x * 4 + w;

    __shared__ float sFC[4][64], sA[4][64], sB[4][64];

    // fused
    sA[w][lane] = sumFeat[(size_t)p * 64 + lane] * invS;
    __syncthreads();

    // fc
    {
        float x = fc_b[lane];
        #pragma unroll 8
        for (int c = 0; c < 64; ++c) x += sA[w][c] * fc_w[c * 64 + lane];
        x = fmaxf(x, 0.f);
        __syncthreads();
        sFC[w][lane] = x;
    }
    __syncthreads();

    float* orow = out + (size_t)p * OUTD;

    // ---- cls ----
    {
        float x = cls_b[lane];
        #pragma unroll 8
        for (int c = 0; c < 64; ++c) x += sFC[w][c] * cls_w[c * 64 + lane];
        x = fmaxf(x, 0.f);
        __syncthreads(); sA[w][lane] = x; __syncthreads();
        float y = cls_b[64 + lane];
        #pragma unroll 8
        for (int c = 0; c < 64; ++c) y += sA[w][c] * cls_w[4096 + c * 64 + lane];
        y = fmaxf(y, 0.f);
        __syncthreads(); sB[w][lane] = y; __syncthreads();
        if (lane < 2) {
            float z = cls_ob[lane];
            #pragma unroll 8
            for (int k = 0; k < 64; ++k) z += sB[w][k] * cls_ow[k * 2 + lane];
            orow[lane] = z;
        }
        __syncthreads();
    }

    // ---- reg ----
    {
        float x = reg_b[lane];
        #pragma unroll 8
        for (int c = 0; c < 64; ++c) x += sFC[w][c] * reg_w[c * 64 + lane];
        x = fmaxf(x, 0.f);
        __syncthreads(); sA[w][lane] = x; __syncthreads();
        float y = reg_b[64 + lane];
        #pragma unroll 8
        for (int c = 0; c < 64; ++c) y += sA[w][c] * reg_w[4096 + c * 64 + lane];
        y = fmaxf(y, 0.f);
        __syncthreads(); sB[w][lane] = y; __syncthreads();
        for (int j = lane; j < REGD; j += 64) {
            float z = reg_ob[j];
            #pragma unroll 8
            for (int k = 0; k < 64; ++k) z += sB[w][k] * reg_ow[k * REGD + j];
            orow[2 + j] = z;
            if (j >= 4) xs_next[(size_t)p * NOq + (j - 4)] = 1.0f / (1.0f + __expf(-z));
        }
        __syncthreads();
    }

    // ---- loc ----
    {
        float x = loc_b[lane];
        #pragma unroll 8
        for (int c = 0; c < 64; ++c) x += sFC[w][c] * loc_w[c * 64 + lane];
        x = fmaxf(x, 0.f);
        __syncthreads(); sA[w][lane] = x; __syncthreads();
        float y = loc_b[64 + lane];
        #pragma unroll 8
        for (int c = 0; c < 64; ++c) y += sA[w][c] * loc_w[4096 + c * 64 + lane];
        y = fmaxf(y, 0.f);
        __syncthreads(); sB[w][lane] = y; __syncthreads();
        if (lane == 0) {
            float z = loc_ob[0];
            #pragma unroll 8
            for (int k = 0; k < 64; ++k) z += sB[w][k] * loc_ow[k];
            orow[78] = z;
        }
    }
}

// ---------------------------------------------------------------------------
extern "C" void kernel_launch(void* const* d_in, const int* in_sizes, int n_in,
                              void* d_out, int out_size, void* d_ws, size_t ws_size,
                              hipStream_t stream)
{
    const float* x0        = (const float*)d_in[0];
    const float* x1        = (const float*)d_in[1];
    const float* x2        = (const float*)d_in[2];
    const float* prior_xs0 = (const float*)d_in[3];
    const float* l_weight  = (const float*)d_in[4];
    const float* lsgi_w    = (const float*)d_in[5];
    const float* fc_w      = (const float*)d_in[6];
    const float* fc_b      = (const float*)d_in[7];
    const float* cls_w     = (const float*)d_in[8];
    const float* cls_b     = (const float*)d_in[9];
    const float* cls_ow    = (const float*)d_in[10];
    const float* cls_ob    = (const float*)d_in[11];
    const float* reg_w     = (const float*)d_in[12];
    const float* reg_b     = (const float*)d_in[13];
    const float* reg_ow    = (const float*)d_in[14];
    const float* reg_ob    = (const float*)d_in[15];
    const float* loc_w     = (const float*)d_in[16];
    const float* loc_b     = (const float*)d_in[17];
    const float* loc_ow    = (const float*)d_in[18];
    const float* loc_ob    = (const float*)d_in[19];

    float* out     = (float*)d_out;
    float* sumFeat = (float*)d_ws;                       // [6144*64]
    float* xs      = sumFeat + (size_t)Bq * NPq * Cq;    // [6144*72]

    const float* feats[3] = {x2, x1, x0};
    const int Hs[3]  = {10, 20, 40};
    const int Wss[3] = {25, 50, 100};

    for (int s = 0; s < 3; ++s) {
        const float* xsrc = (s == 0) ? prior_xs0 : xs;
        const int bstr    = (s == 0) ? 0 : NPq * NOq;
        hipLaunchKernelGGL(sample_gemm_kernel, dim3(Bq * NPq), dim3(256), 0, stream,
                           feats[s], Hs[s], Wss[s], xsrc, bstr,
                           lsgi_w + s * 4096, l_weight, sumFeat, (s > 0) ? 1 : 0);
        hipLaunchKernelGGL(head_kernel, dim3(Bq * NPq / 4), dim3(256), 0, stream,
                           sumFeat, 1.0f / (float)(s + 1),
                           fc_w, fc_b, cls_w, cls_b, cls_ow, cls_ob,
                           reg_w, reg_b, reg_ow, reg_ob,
                           loc_w, loc_b, loc_ow, loc_ob,
                           out + (size_t)s * Bq * NPq * OUTD, xs);
    }
}

// Round 2
// 481.412 us; speedup vs baseline: 1.6171x; 1.6171x over previous
//
#include <hip/hip_runtime.h>

#define Bq   32
#define Cq   64
#define NPq  192
#define NOq  72
#define PTS  (NPq * NOq)   // 13824
#define REGD 76
#define OUTD 79

// ---------------------------------------------------------------------------
// Phase 1: per (b, channel-pair) block.  Build gated y-blended row table in
// LDS (rb[ch][o][x], padded x column), then 1-D linear interp per point from
// LDS, write pooled[bl][c][pt] coalesced.
// ---------------------------------------------------------------------------
template<int H, int W>
__global__ __launch_bounds__(256) void rowblend_gather_kernel(
    const float* __restrict__ feat,   // [B][C][H][W]
    const float* __restrict__ xsrc,   // [B][PTS] or [PTS]
    const int xstride,                // PTS or 0
    const float* __restrict__ lw,     // [72]
    float* __restrict__ pooled,       // [Bc][C][PTS]
    const int b0)
{
    constexpr int Wp = W + 1;
    __shared__ float sRB[2 * NOq * Wp];
    __shared__ float sWy[NOq], sGate[NOq];
    __shared__ int   sIy0W[NOq], sIy1W[NOq];

    const int tid = threadIdx.x;
    const int bl  = blockIdx.x >> 5;
    const int cg  = blockIdx.x & 31;
    const int b   = b0 + bl;
    const int c0  = cg * 2;

    if (tid < NOq) {
        const float ys = 1.0f - (float)tid * (1.0f / 71.0f);
        const float iy = ys * (float)(H - 1);
        const float fy = floorf(iy);
        sWy[tid] = iy - fy;
        int iy0 = (int)fy; iy0 = iy0 < 0 ? 0 : (iy0 > H - 1 ? H - 1 : iy0);
        const int iy1 = (iy0 + 1 > H - 1) ? H - 1 : iy0 + 1;
        sIy0W[tid] = iy0 * W;
        sIy1W[tid] = iy1 * W;
        sGate[tid] = 1.0f / (1.0f + __expf(-lw[tid]));
    }
    __syncthreads();

    // build gated row-blend table (coalesced global row reads)
    const float* fbase = feat + (size_t)(b * Cq + c0) * (H * W);
    constexpr int TOT = 2 * NOq * W;
    for (int idx = tid; idx < TOT; idx += 256) {
        const int row = idx / W;
        const int x   = idx - row * W;
        const int ch  = row / NOq;
        const int o   = row - ch * NOq;
        const float wy = sWy[o];
        const float* f = fbase + ch * (H * W);
        const float v = (1.0f - wy) * f[sIy0W[o] + x] + wy * f[sIy1W[o] + x];
        sRB[row * Wp + x] = v * sGate[o];
    }
    __syncthreads();
    if (tid < 2 * NOq) sRB[tid * Wp + W] = sRB[tid * Wp + W - 1];
    __syncthreads();

    // gather: 2 adjacent LDS reads per (pt, ch)
    const float* xp = xsrc + (size_t)xstride * b;
    float* p0 = pooled + (size_t)(bl * Cq + c0) * PTS;
    float* p1 = p0 + PTS;
    #pragma unroll 2
    for (int it = 0; it < PTS / 256; ++it) {
        const int pt = it * 256 + tid;
        const int o  = pt % NOq;
        const float xv  = xp[pt];
        const float ixf = xv * (float)(W - 1);
        const float fx  = floorf(ixf);
        const float wx  = ixf - fx;
        int ix0 = (int)fx; ix0 = ix0 < 0 ? 0 : (ix0 > W - 1 ? W - 1 : ix0);
        const int base = o * Wp + ix0;
        const float a0 = sRB[base],           a1 = sRB[base + 1];
        const float c0v = sRB[NOq * Wp + base], c1v = sRB[NOq * Wp + base + 1];
        p0[pt] = a0  + wx * (a1  - a0);
        p1[pt] = c0v + wx * (c1v - c0v);
    }
}

// ---------------------------------------------------------------------------
// Phase 2: per (b, n-pair) block.  A^T(64x144)+W(64x64) in LDS, register-
// tiled fp32 GEMM (9o x 4d per thread), relu -> pairmax -> mean/36 ->
// accumulate sumFeat.
// ---------------------------------------------------------------------------
__global__ __launch_bounds__(256) void gemm_pool_kernel(
    const float* __restrict__ pooled,  // [Bc][C][PTS]
    const float* __restrict__ lsgi,    // [64*64] this stage
    float* __restrict__ sumFeat,       // [B*NP, 64]
    const int b0, const int accumulate)
{
    __shared__ __align__(16) float sW[64 * 64];     // 16 KB
    __shared__ __align__(16) float sA[64 * 144];    // 36.9 KB (reused as out)
    __shared__ float sRed[4 * 64];

    const int tid   = threadIdx.x;
    const int bl    = blockIdx.x / 96;
    const int npair = blockIdx.x - bl * 96;
    const int n0    = npair * 2;
    const int b     = b0 + bl;

    #pragma unroll
    for (int i = 0; i < 16; ++i) sW[tid + i * 256] = lsgi[tid + i * 256];

    // stage A^T: sA[c][i], i = 0..143 over the two n's (float4 loads)
    {
        const float* srcBase = pooled + (size_t)(bl * Cq) * PTS + n0 * NOq;
        #pragma unroll
        for (int j = 0; j < 9; ++j) {
            const int flat4 = j * 256 + tid;       // [0, 2304)
            const int c   = flat4 / 36;
            const int rem = flat4 - c * 36;
            const float4 v = *(const float4*)(srcBase + (size_t)c * PTS + rem * 4);
            *(float4*)&sA[c * 144 + rem * 4] = v;
        }
    }
    __syncthreads();

    // GEMM
    const int h  = tid >> 7;          // n-half
    const int t  = tid & 127;
    const int og = t >> 4;            // 0..7  -> o0 = og*9
    const int dg = t & 15;            // 0..15 -> d0 = dg*4
    const int o0 = og * 9;
    const int d0 = dg * 4;
    float acc[9][4];
    #pragma unroll
    for (int j = 0; j < 9; ++j) { acc[j][0] = acc[j][1] = acc[j][2] = acc[j][3] = 0.f; }

    const float* Ah = sA + h * NOq + o0;
    #pragma unroll 4
    for (int k = 0; k < 64; ++k) {
        const float4 w = *(const float4*)&sW[k * 64 + d0];
        const float* ar = Ah + k * 144;
        #pragma unroll
        for (int j = 0; j < 9; ++j) {
            const float a = ar[j];
            acc[j][0] += a * w.x; acc[j][1] += a * w.y;
            acc[j][2] += a * w.z; acc[j][3] += a * w.w;
        }
    }
    __syncthreads();   // all GEMM reads of sA done

    // relu -> sOut (reuse sA): [h*72+o][d]
    float* sOut = sA;
    #pragma unroll
    for (int j = 0; j < 9; ++j) {
        float4 v;
        v.x = fmaxf(acc[j][0], 0.f); v.y = fmaxf(acc[j][1], 0.f);
        v.z = fmaxf(acc[j][2], 0.f); v.w = fmaxf(acc[j][3], 0.f);
        *(float4*)&sOut[(h * NOq + o0 + j) * 64 + d0] = v;
    }
    __syncthreads();

    // pairmax over o, partial sums (q halves of 18 pairs each)
    {
        const int d  = tid & 63;
        const int h2 = (tid >> 6) & 1;
        const int q  = tid >> 7;
        float s = 0.f;
        #pragma unroll
        for (int j = 0; j < 18; ++j) {
            const int o2 = q * 18 + j;
            s += fmaxf(sOut[(h2 * NOq + 2 * o2) * 64 + d],
                       sOut[(h2 * NOq + 2 * o2 + 1) * 64 + d]);
        }
        sRed[(h2 * 2 + q) * 64 + d] = s;
    }
    __syncthreads();
    if (tid < 128) {
        const int h2 = tid >> 6, d = tid & 63;
        float tot = (sRed[(h2 * 2) * 64 + d] + sRed[(h2 * 2 + 1) * 64 + d]) * (1.0f / 36.0f);
        float* dst = sumFeat + (size_t)(b * NPq + n0 + h2) * 64 + d;
        if (accumulate) tot += *dst;
        *dst = tot;
    }
}

// ---------------------------------------------------------------------------
// Phase 3: heads (unchanged from R1 — verified).
// ---------------------------------------------------------------------------
__global__ __launch_bounds__(256) void head_kernel(
    const float* __restrict__ sumFeat, const float invS,
    const float* __restrict__ fc_w,  const float* __restrict__ fc_b,
    const float* __restrict__ cls_w, const float* __restrict__ cls_b,
    const float* __restrict__ cls_ow, const float* __restrict__ cls_ob,
    const float* __restrict__ reg_w, const float* __restrict__ reg_b,
    const float* __restrict__ reg_ow, const float* __restrict__ reg_ob,
    const float* __restrict__ loc_w, const float* __restrict__ loc_b,
    const float* __restrict__ loc_ow, const float* __restrict__ loc_ob,
    float* __restrict__ out, float* __restrict__ xs_next)
{
    const int w    = threadIdx.x >> 6;
    const int lane = threadIdx.x & 63;
    const int p    = blockIdx.x * 4 + w;

    __shared__ float sFC[4][64], sA[4][64], sB[4][64];

    sA[w][lane] = sumFeat[(size_t)p * 64 + lane] * invS;
    __syncthreads();

    {
        float x = fc_b[lane];
        #pragma unroll 8
        for (int c = 0; c < 64; ++c) x += sA[w][c] * fc_w[c * 64 + lane];
        x = fmaxf(x, 0.f);
        __syncthreads();
        sFC[w][lane] = x;
    }
    __syncthreads();

    float* orow = out + (size_t)p * OUTD;

    // ---- cls ----
    {
        float x = cls_b[lane];
        #pragma unroll 8
        for (int c = 0; c < 64; ++c) x += sFC[w][c] * cls_w[c * 64 + lane];
        x = fmaxf(x, 0.f);
        __syncthreads(); sA[w][lane] = x; __syncthreads();
        float y = cls_b[64 + lane];
        #pragma unroll 8
        for (int c = 0; c < 64; ++c) y += sA[w][c] * cls_w[4096 + c * 64 + lane];
        y = fmaxf(y, 0.f);
        __syncthreads(); sB[w][lane] = y; __syncthreads();
        if (lane < 2) {
            float z = cls_ob[lane];
            #pragma unroll 8
            for (int k = 0; k < 64; ++k) z += sB[w][k] * cls_ow[k * 2 + lane];
            orow[lane] = z;
        }
        __syncthreads();
    }

    // ---- reg ----
    {
        float x = reg_b[lane];
        #pragma unroll 8
        for (int c = 0; c < 64; ++c) x += sFC[w][c] * reg_w[c * 64 + lane];
        x = fmaxf(x, 0.f);
        __syncthreads(); sA[w][lane] = x; __syncthreads();
        float y = reg_b[64 + lane];
        #pragma unroll 8
        for (int c = 0; c < 64; ++c) y += sA[w][c] * reg_w[4096 + c * 64 + lane];
        y = fmaxf(y, 0.f);
        __syncthreads(); sB[w][lane] = y; __syncthreads();
        for (int j = lane; j < REGD; j += 64) {
            float z = reg_ob[j];
            #pragma unroll 8
            for (int k = 0; k < 64; ++k) z += sB[w][k] * reg_ow[k * REGD + j];
            orow[2 + j] = z;
            if (j >= 4) xs_next[(size_t)p * NOq + (j - 4)] = 1.0f / (1.0f + __expf(-z));
        }
        __syncthreads();
    }

    // ---- loc ----
    {
        float x = loc_b[lane];
        #pragma unroll 8
        for (int c = 0; c < 64; ++c) x += sFC[w][c] * loc_w[c * 64 + lane];
        x = fmaxf(x, 0.f);
        __syncthreads(); sA[w][lane] = x; __syncthreads();
        float y = loc_b[64 + lane];
        #pragma unroll 8
        for (int c = 0; c < 64; ++c) y += sA[w][c] * loc_w[4096 + c * 64 + lane];
        y = fmaxf(y, 0.f);
        __syncthreads(); sB[w][lane] = y; __syncthreads();
        if (lane == 0) {
            float z = loc_ob[0];
            #pragma unroll 8
            for (int k = 0; k < 64; ++k) z += sB[w][k] * loc_ow[k];
            orow[78] = z;
        }
    }
}

// ---------------------------------------------------------------------------
extern "C" void kernel_launch(void* const* d_in, const int* in_sizes, int n_in,
                              void* d_out, int out_size, void* d_ws, size_t ws_size,
                              hipStream_t stream)
{
    const float* x0        = (const float*)d_in[0];
    const float* x1        = (const float*)d_in[1];
    const float* x2        = (const float*)d_in[2];
    const float* prior_xs0 = (const float*)d_in[3];
    const float* l_weight  = (const float*)d_in[4];
    const float* lsgi_w    = (const float*)d_in[5];
    const float* fc_w      = (const float*)d_in[6];
    const float* fc_b      = (const float*)d_in[7];
    const float* cls_w     = (const float*)d_in[8];
    const float* cls_b     = (const float*)d_in[9];
    const float* cls_ow    = (const float*)d_in[10];
    const float* cls_ob    = (const float*)d_in[11];
    const float* reg_w     = (const float*)d_in[12];
    const float* reg_b     = (const float*)d_in[13];
    const float* reg_ow    = (const float*)d_in[14];
    const float* reg_ob    = (const float*)d_in[15];
    const float* loc_w     = (const float*)d_in[16];
    const float* loc_b     = (const float*)d_in[17];
    const float* loc_ow    = (const float*)d_in[18];
    const float* loc_ob    = (const float*)d_in[19];

    float* out     = (float*)d_out;
    float* sumFeat = (float*)d_ws;                       // [6144*64]
    float* xs      = sumFeat + (size_t)Bq * NPq * Cq;    // [6144*72]
    float* pooled  = xs + (size_t)Bq * PTS;              // [Bc][64][PTS]

    // dynamic batch-chunking so pooled fits in ws
    const size_t fixed_bytes = ((size_t)Bq * NPq * Cq + (size_t)Bq * PTS) * 4;
    const size_t per_b       = (size_t)Cq * PTS * 4;     // 3.54 MB
    int Bc = Bq;
    if (ws_size < fixed_bytes + (size_t)Bq * per_b) {
        Bc = (int)((ws_size - fixed_bytes) / per_b);
        if (Bc < 1) Bc = 1;
        if (Bc > Bq) Bc = Bq;
    }

    const float* feats[3] = {x2, x1, x0};

    for (int s = 0; s < 3; ++s) {
        const float* xsrc = (s == 0) ? prior_xs0 : xs;
        const int xstr    = (s == 0) ? 0 : PTS;
        for (int c0 = 0; c0 < Bq; c0 += Bc) {
            const int bc = (Bc < Bq - c0) ? Bc : (Bq - c0);
            if (s == 0)
                hipLaunchKernelGGL((rowblend_gather_kernel<10, 25>), dim3(bc * 32), dim3(256), 0, stream,
                                   feats[0], xsrc, xstr, l_weight, pooled, c0);
            else if (s == 1)
                hipLaunchKernelGGL((rowblend_gather_kernel<20, 50>), dim3(bc * 32), dim3(256), 0, stream,
                                   feats[1], xsrc, xstr, l_weight, pooled, c0);
            else
                hipLaunchKernelGGL((rowblend_gather_kernel<40, 100>), dim3(bc * 32), dim3(256), 0, stream,
                                   feats[2], xsrc, xstr, l_weight, pooled, c0);
            hipLaunchKernelGGL(gemm_pool_kernel, dim3(bc * 96), dim3(256), 0, stream,
                               pooled, lsgi_w + s * 4096, sumFeat, c0, (s > 0) ? 1 : 0);
        }
        hipLaunchKernelGGL(head_kernel, dim3(Bq * NPq / 4), dim3(256), 0, stream,
                           sumFeat, 1.0f / (float)(s + 1),
                           fc_w, fc_b, cls_w, cls_b, cls_ow, cls_ob,
                           reg_w, reg_b, reg_ow, reg_ob,
                           loc_w, loc_b, loc_ow, loc_ob,
                           out + (size_t)s * Bq * NPq * OUTD, xs);
    }
}

// Round 3
// 481.353 us; speedup vs baseline: 1.6173x; 1.0001x over previous
//
#include <hip/hip_runtime.h>
#include <hip/hip_bf16.h>

#define Bq   32
#define Cq   64
#define NPq  192
#define NOq  72
#define PTS  (NPq * NOq)   // 13824
#define NTB  (PTS / 16)    // 864 pt-tiles per batch
#define FRAG_PER_B ((size_t)NTB * 2 * 64 * 8)   // ushorts per batch = 884736
#define REGD 76
#define OUTD 79

typedef __attribute__((ext_vector_type(8))) short short8;
typedef __attribute__((ext_vector_type(4))) float float4v;

__device__ inline unsigned short f2bf(float x) {
    __hip_bfloat16 h = __float2bfloat16(x);
    return *reinterpret_cast<unsigned short*>(&h);
}

// ---------------------------------------------------------------------------
// Phase 1: per (b, channel-octet) block.  o processed in 6 chunks of 12:
// build fp32 gated row-blend table in LDS, then per point do 1-D lerp for the
// 8 channels and store one 16-B bf16 fragment chunk (MFMA A-frag order).
// pooled layout: [b][nt][ks][lane][j] bf16,
//   nt=pt>>4, ks=c>>5, lane=(pt&15)+16*((c>>3)&3), j=c&7.
// ---------------------------------------------------------------------------
template<int H, int W>
__global__ __launch_bounds__(256) void rowblend_kernel(
    const float* __restrict__ feat,   // [B][C][H][W]
    const float* __restrict__ xsrc,   // [B][PTS] or [PTS]
    const int xstride,
    const float* __restrict__ lw,     // [72]
    unsigned short* __restrict__ pooled,
    const int b0)
{
    constexpr int Wp  = W + 1;
    constexpr int OCH = 12;
    __shared__ float sT[8 * OCH * Wp];
    __shared__ float sWy[NOq], sGate[NOq];
    __shared__ int   sIy0W[NOq], sIy1W[NOq];

    const int tid = threadIdx.x;
    const int bl  = blockIdx.x >> 3;
    const int cg  = blockIdx.x & 7;
    const int b   = b0 + bl;
    const int c0  = cg * 8;

    if (tid < NOq) {
        const float ys = 1.0f - (float)tid * (1.0f / 71.0f);
        const float iy = ys * (float)(H - 1);
        const float fy = floorf(iy);
        sWy[tid] = iy - fy;
        int iy0 = (int)fy; iy0 = iy0 < 0 ? 0 : (iy0 > H - 1 ? H - 1 : iy0);
        const int iy1 = (iy0 + 1 > H - 1) ? H - 1 : iy0 + 1;
        sIy0W[tid] = iy0 * W;
        sIy1W[tid] = iy1 * W;
        sGate[tid] = 1.0f / (1.0f + __expf(-lw[tid]));
    }
    __syncthreads();

    const float* fbase = feat + (size_t)(b * Cq + c0) * (H * W);
    const float* xp    = xsrc + (size_t)xstride * b;
    unsigned short* pb = pooled + (size_t)bl * FRAG_PER_B;
    const int ks   = cg >> 2;
    const int lofs = 16 * (cg & 3);

    for (int oc = 0; oc < 6; ++oc) {
        // build table for this o-chunk (coalesced row reads)
        constexpr int TOT = 8 * OCH * W;
        for (int idx = tid; idx < TOT; idx += 256) {
            const int row = idx / W;          // c*12 + ol
            const int x   = idx - row * W;
            const int c   = row / OCH;
            const int ol  = row - c * OCH;
            const int o   = oc * OCH + ol;
            const float wy = sWy[o];
            const float* f = fbase + c * (H * W);
            const float v = (1.0f - wy) * f[sIy0W[o] + x] + wy * f[sIy1W[o] + x];
            sT[row * Wp + x] = v * sGate[o];
        }
        __syncthreads();
        if (tid < 8 * OCH) sT[tid * Wp + W] = sT[tid * Wp + W - 1];
        __syncthreads();

        // gather + fragment store: 192 n x 12 o = 2304 points, 9 per thread
        #pragma unroll
        for (int i = 0; i < 9; ++i) {
            const int ptl = i * 256 + tid;
            const int n   = ptl / OCH;
            const int ol  = ptl - n * OCH;
            const int o   = oc * OCH + ol;
            const int pt  = n * NOq + o;
            float ixf = xp[pt] * (float)(W - 1);
            ixf = fminf(fmaxf(ixf, 0.0f), (float)(W - 1));
            const float fx = floorf(ixf);
            const float wx = ixf - fx;
            const int ix0 = (int)fx;
            union { unsigned short u[8]; short8 v; } pk;
            #pragma unroll
            for (int c = 0; c < 8; ++c) {
                const float a0 = sT[(c * OCH + ol) * Wp + ix0];
                const float a1 = sT[(c * OCH + ol) * Wp + ix0 + 1];
                pk.u[c] = f2bf(a0 + wx * (a1 - a0));
            }
            const int nt = pt >> 4;
            const int l  = (pt & 15) + lofs;
            *(short8*)(pb + ((((size_t)nt * 2 + ks) * 64 + l) << 3)) = pk.v;
        }
        __syncthreads();
    }
}

// ---------------------------------------------------------------------------
// Phase 2: MFMA pool.  Block = (b, group of 8 n); each wave owns an n-pair
// (144 pts = 9 tiles).  W-frags in VGPRs; pooled frags straight from global.
// No LDS.  Epilogue: relu -> pairmax -> mean/36 -> accumulate sumFeat.
// ---------------------------------------------------------------------------
__global__ __launch_bounds__(256) void mfma_pool_kernel(
    const unsigned short* __restrict__ pooled,
    const float* __restrict__ lsgi,    // [64][64] this stage
    float* __restrict__ sumFeat,       // [B*NP][64]
    const int b0, const int accumulate)
{
    const int tid  = threadIdx.x;
    const int w    = tid >> 6;
    const int lane = tid & 63;
    const int bl    = blockIdx.x / 24;
    const int ng    = blockIdx.x - bl * 24;
    const int npair = ng * 4 + w;      // 0..95
    const int b     = b0 + bl;

    // build W B-frags: wf[dt][ks], lane holds B[k=ks*32+(lane>>4)*8+j][n=dt*16+(lane&15)]
    short8 wf[4][2];
    {
        const int kb = ((lane >> 4) & 3) * 8;
        const int dl = lane & 15;
        #pragma unroll
        for (int ks = 0; ks < 2; ++ks)
            #pragma unroll
            for (int dt = 0; dt < 4; ++dt) {
                union { unsigned short u[8]; short8 v; } pk;
                #pragma unroll
                for (int j = 0; j < 8; ++j)
                    pk.u[j] = f2bf(lsgi[(ks * 32 + kb + j) * 64 + dt * 16 + dl]);
                wf[dt][ks] = pk.v;
            }
    }

    const unsigned short* pbase = pooled + (size_t)bl * FRAG_PER_B;
    const int nt0 = npair * 9;

    float sums0[4] = {0.f, 0.f, 0.f, 0.f};
    float sums1[4] = {0.f, 0.f, 0.f, 0.f};

    #pragma unroll
    for (int ntl = 0; ntl < 9; ++ntl) {
        const size_t fbase = (((size_t)(nt0 + ntl) * 2) * 64 + lane) << 3;
        const short8 a0 = *(const short8*)(pbase + fbase);
        const short8 a1 = *(const short8*)(pbase + fbase + 512);
        const bool hi = (ntl * 16 + ((lane >> 4) * 4)) >= NOq;
        #pragma unroll
        for (int dt = 0; dt < 4; ++dt) {
            float4v c = {0.f, 0.f, 0.f, 0.f};
            c = __builtin_amdgcn_mfma_f32_16x16x32_bf16(a0, wf[dt][0], c, 0, 0, 0);
            c = __builtin_amdgcn_mfma_f32_16x16x32_bf16(a1, wf[dt][1], c, 0, 0, 0);
            const float pm0 = fmaxf(fmaxf(c[0], c[1]), 0.f);
            const float pm1 = fmaxf(fmaxf(c[2], c[3]), 0.f);
            const float add = pm0 + pm1;
            if (hi) sums1[dt] += add; else sums0[dt] += add;
        }
    }

    // reduce over the 4 quad-lanes
    #pragma unroll
    for (int dt = 0; dt < 4; ++dt) {
        float v0 = sums0[dt], v1 = sums1[dt];
        v0 += __shfl_xor(v0, 16); v0 += __shfl_xor(v0, 32);
        v1 += __shfl_xor(v1, 16); v1 += __shfl_xor(v1, 32);
        sums0[dt] = v0; sums1[dt] = v1;
    }

    if (lane < 16) {
        const size_t row0 = (size_t)(b * NPq + npair * 2) * 64;
        #pragma unroll
        for (int dt = 0; dt < 4; ++dt) {
            const int d = dt * 16 + lane;
            float t0 = sums0[dt] * (1.0f / 36.0f);
            float t1 = sums1[dt] * (1.0f / 36.0f);
            float* p0 = sumFeat + row0 + d;
            float* p1 = sumFeat + row0 + 64 + d;
            if (accumulate) { t0 += *p0; t1 += *p1; }
            *p0 = t0; *p1 = t1;
        }
    }
}

// ---------------------------------------------------------------------------
// Phase 3: heads.  4 waves/block, 4 points/wave (weight loads reused x4).
// ---------------------------------------------------------------------------
__global__ __launch_bounds__(256) void head_kernel(
    const float* __restrict__ sumFeat, const float invS,
    const float* __restrict__ fc_w,  const float* __restrict__ fc_b,
    const float* __restrict__ cls_w, const float* __restrict__ cls_b,
    const float* __restrict__ cls_ow, const float* __restrict__ cls_ob,
    const float* __restrict__ reg_w, const float* __restrict__ reg_b,
    const float* __restrict__ reg_ow, const float* __restrict__ reg_ob,
    const float* __restrict__ loc_w, const float* __restrict__ loc_b,
    const float* __restrict__ loc_ow, const float* __restrict__ loc_ob,
    float* __restrict__ out, float* __restrict__ xs_next)
{
    const int w    = threadIdx.x >> 6;
    const int lane = threadIdx.x & 63;
    const int r0   = w * 4;                       // this wave's LDS rows
    const int p0   = blockIdx.x * 16 + r0;        // global point base

    __shared__ float sFC[16][64];
    __shared__ float sT[16][64];

    float y[4];

    // fused -> sT
    #pragma unroll
    for (int p = 0; p < 4; ++p)
        sT[r0 + p][lane] = sumFeat[(size_t)(p0 + p) * 64 + lane] * invS;
    __syncthreads();

    // fc -> sFC
    y[0] = y[1] = y[2] = y[3] = fc_b[lane];
    for (int c = 0; c < 64; ++c) {
        const float wv = fc_w[c * 64 + lane];
        #pragma unroll
        for (int p = 0; p < 4; ++p) y[p] += sT[r0 + p][c] * wv;
    }
    __syncthreads();
    #pragma unroll
    for (int p = 0; p < 4; ++p) sFC[r0 + p][lane] = fmaxf(y[p], 0.f);
    __syncthreads();

    // ---------------- cls ----------------
    y[0] = y[1] = y[2] = y[3] = cls_b[lane];
    for (int c = 0; c < 64; ++c) {
        const float wv = cls_w[c * 64 + lane];
        #pragma unroll
        for (int p = 0; p < 4; ++p) y[p] += sFC[r0 + p][c] * wv;
    }
    __syncthreads();
    #pragma unroll
    for (int p = 0; p < 4; ++p) sT[r0 + p][lane] = fmaxf(y[p], 0.f);
    __syncthreads();
    y[0] = y[1] = y[2] = y[3] = cls_b[64 + lane];
    for (int c = 0; c < 64; ++c) {
        const float wv = cls_w[4096 + c * 64 + lane];
        #pragma unroll
        for (int p = 0; p < 4; ++p) y[p] += sT[r0 + p][c] * wv;
    }
    __syncthreads();
    #pragma unroll
    for (int p = 0; p < 4; ++p) sT[r0 + p][lane] = fmaxf(y[p], 0.f);
    __syncthreads();
    if (lane < 8) {
        const int p = lane >> 1, d = lane & 1;
        float z = cls_ob[d];
        for (int k = 0; k < 64; ++k) z += sT[r0 + p][k] * cls_ow[k * 2 + d];
        out[(size_t)(p0 + p) * OUTD + d] = z;
    }
    __syncthreads();

    // ---------------- reg ----------------
    y[0] = y[1] = y[2] = y[3] = reg_b[lane];
    for (int c = 0; c < 64; ++c) {
        const float wv = reg_w[c * 64 + lane];
        #pragma unroll
        for (int p = 0; p < 4; ++p) y[p] += sFC[r0 + p][c] * wv;
    }
    __syncthreads();
    #pragma unroll
    for (int p = 0; p < 4; ++p) sT[r0 + p][lane] = fmaxf(y[p], 0.f);
    __syncthreads();
    y[0] = y[1] = y[2] = y[3] = reg_b[64 + lane];
    for (int c = 0; c < 64; ++c) {
        const float wv = reg_w[4096 + c * 64 + lane];
        #pragma unroll
        for (int p = 0; p < 4; ++p) y[p] += sT[r0 + p][c] * wv;
    }
    __syncthreads();
    #pragma unroll
    for (int p = 0; p < 4; ++p) sT[r0 + p][lane] = fmaxf(y[p], 0.f);
    __syncthreads();
    {
        const bool g2 = lane < (REGD - 64);     // lane < 12
        const int j0 = lane;
        const int j1 = 64 + (g2 ? lane : 0);
        #pragma unroll
        for (int p = 0; p < 4; ++p) {
            float z0 = reg_ob[j0];
            float z1 = g2 ? reg_ob[j1] : 0.f;
            for (int k = 0; k < 64; ++k) {
                const float av = sT[r0 + p][k];
                z0 += av * reg_ow[k * REGD + j0];
                if (g2) z1 += av * reg_ow[k * REGD + j1];
            }
            float* orow = out + (size_t)(p0 + p) * OUTD;
            float* xsp  = xs_next + (size_t)(p0 + p) * NOq;
            orow[2 + j0] = z0;
            if (j0 >= 4) xsp[j0 - 4] = 1.0f / (1.0f + __expf(-z0));
            if (g2) {
                orow[2 + j1] = z1;
                xsp[j1 - 4] = 1.0f / (1.0f + __expf(-z1));
            }
        }
    }
    __syncthreads();

    // ---------------- loc ----------------
    y[0] = y[1] = y[2] = y[3] = loc_b[lane];
    for (int c = 0; c < 64; ++c) {
        const float wv = loc_w[c * 64 + lane];
        #pragma unroll
        for (int p = 0; p < 4; ++p) y[p] += sFC[r0 + p][c] * wv;
    }
    __syncthreads();
    #pragma unroll
    for (int p = 0; p < 4; ++p) sT[r0 + p][lane] = fmaxf(y[p], 0.f);
    __syncthreads();
    y[0] = y[1] = y[2] = y[3] = loc_b[64 + lane];
    for (int c = 0; c < 64; ++c) {
        const float wv = loc_w[4096 + c * 64 + lane];
        #pragma unroll
        for (int p = 0; p < 4; ++p) y[p] += sT[r0 + p][c] * wv;
    }
    __syncthreads();
    #pragma unroll
    for (int p = 0; p < 4; ++p) sT[r0 + p][lane] = fmaxf(y[p], 0.f);
    __syncthreads();
    if (lane < 4) {
        const int p = lane;
        float z = loc_ob[0];
        for (int k = 0; k < 64; ++k) z += sT[r0 + p][k] * loc_ow[k];
        out[(size_t)(p0 + p) * OUTD + 78] = z;
    }
}

// ---------------------------------------------------------------------------
extern "C" void kernel_launch(void* const* d_in, const int* in_sizes, int n_in,
                              void* d_out, int out_size, void* d_ws, size_t ws_size,
                              hipStream_t stream)
{
    const float* x0        = (const float*)d_in[0];
    const float* x1        = (const float*)d_in[1];
    const float* x2        = (const float*)d_in[2];
    const float* prior_xs0 = (const float*)d_in[3];
    const float* l_weight  = (const float*)d_in[4];
    const float* lsgi_w    = (const float*)d_in[5];
    const float* fc_w      = (const float*)d_in[6];
    const float* fc_b      = (const float*)d_in[7];
    const float* cls_w     = (const float*)d_in[8];
    const float* cls_b     = (const float*)d_in[9];
    const float* cls_ow    = (const float*)d_in[10];
    const float* cls_ob    = (const float*)d_in[11];
    const float* reg_w     = (const float*)d_in[12];
    const float* reg_b     = (const float*)d_in[13];
    const float* reg_ow    = (const float*)d_in[14];
    const float* reg_ob    = (const float*)d_in[15];
    const float* loc_w     = (const float*)d_in[16];
    const float* loc_b     = (const float*)d_in[17];
    const float* loc_ow    = (const float*)d_in[18];
    const float* loc_ob    = (const float*)d_in[19];

    float* out     = (float*)d_out;
    float* sumFeat = (float*)d_ws;                               // [6144][64] f32
    float* xs      = sumFeat + (size_t)Bq * NPq * Cq;            // [6144][72] f32
    unsigned short* pooled = (unsigned short*)(xs + (size_t)Bq * PTS);

    // batch-chunking so pooled (bf16 frag order) fits in ws
    const size_t fixed_bytes = ((size_t)Bq * NPq * Cq + (size_t)Bq * PTS) * 4;
    const size_t per_b       = FRAG_PER_B * 2;                   // 1.77 MB
    int Bc = Bq;
    if (ws_size < fixed_bytes + (size_t)Bq * per_b) {
        Bc = (int)((ws_size - fixed_bytes) / per_b);
        if (Bc < 1) Bc = 1;
        if (Bc > Bq) Bc = Bq;
    }

    for (int s = 0; s < 3; ++s) {
        const float* xsrc = (s == 0) ? prior_xs0 : xs;
        const int xstr    = (s == 0) ? 0 : PTS;
        for (int c0 = 0; c0 < Bq; c0 += Bc) {
            const int bc = (Bc < Bq - c0) ? Bc : (Bq - c0);
            if (s == 0)
                hipLaunchKernelGGL((rowblend_kernel<10, 25>), dim3(bc * 8), dim3(256), 0, stream,
                                   x2, xsrc, xstr, l_weight, pooled, c0);
            else if (s == 1)
                hipLaunchKernelGGL((rowblend_kernel<20, 50>), dim3(bc * 8), dim3(256), 0, stream,
                                   x1, xsrc, xstr, l_weight, pooled, c0);
            else
                hipLaunchKernelGGL((rowblend_kernel<40, 100>), dim3(bc * 8), dim3(256), 0, stream,
                                   x0, xsrc, xstr, l_weight, pooled, c0);
            hipLaunchKernelGGL(mfma_pool_kernel, dim3(bc * 24), dim3(256), 0, stream,
                               pooled, lsgi_w + s * 4096, sumFeat, c0, (s > 0) ? 1 : 0);
        }
        hipLaunchKernelGGL(head_kernel, dim3(Bq * NPq / 16), dim3(256), 0, stream,
                           sumFeat, 1.0f / (float)(s + 1),
                           fc_w, fc_b, cls_w, cls_b, cls_ow, cls_ob,
                           reg_w, reg_b, reg_ow, reg_ob,
                           loc_w, loc_b, loc_ow, loc_ob,
                           out + (size_t)s * Bq * NPq * OUTD, xs);
    }
}

// Round 4
// 360.769 us; speedup vs baseline: 2.1579x; 1.3342x over previous
//
#include <hip/hip_runtime.h>
#include <hip/hip_bf16.h>

#define Bq   32
#define Cq   64
#define NPq  192
#define NOq  72
#define PTS  (NPq * NOq)   // 13824
#define NTB  (PTS / 16)    // 864 pt-tiles per batch
#define FRAG_PER_B ((size_t)NTB * 2 * 64 * 8)   // ushorts per batch = 884736
#define REGD 76
#define OUTD 79

typedef __attribute__((ext_vector_type(8))) short short8;
typedef __attribute__((ext_vector_type(4))) float float4v;

__device__ inline unsigned short f2bf(float x) {
    __hip_bfloat16 h = __float2bfloat16(x);
    return *reinterpret_cast<unsigned short*>(&h);
}

// ---------------------------------------------------------------------------
// Phase 1: block = (b, channel-octet, o-chunk-of-8).  Build fp32 gated
// row-blend table in LDS for 8 ch x 8 o, then per point 1-D lerp for the 8
// channels and store one 16-B bf16 fragment chunk (MFMA A-frag order).
// pooled layout: [b][nt][ks][lane][j] bf16,
//   nt=pt>>4, ks=c>>5, lane=(pt&15)+16*((c>>3)&3), j=c&7.
// ---------------------------------------------------------------------------
template<int H, int W>
__global__ __launch_bounds__(256) void rowblend_kernel(
    const float* __restrict__ feat,   // [B][C][H][W]
    const float* __restrict__ xsrc,   // [B][PTS] or [PTS]
    const int xstride,
    const float* __restrict__ lw,     // [72]
    unsigned short* __restrict__ pooled,
    const int b0)
{
    constexpr int Wp  = W + 1;
    constexpr int OCH = 8;
    __shared__ float sT[8 * OCH * Wp];
    __shared__ float sWy[NOq], sGate[NOq];
    __shared__ int   sIy0W[NOq], sIy1W[NOq];

    const int tid = threadIdx.x;
    const int bl  = blockIdx.x / 72;
    const int rem = blockIdx.x - bl * 72;
    const int cg  = rem & 7;           // channel octet
    const int oc  = rem >> 3;          // o-chunk 0..8
    const int b   = b0 + bl;
    const int c0  = cg * 8;

    if (tid < NOq) {
        const float ys = 1.0f - (float)tid * (1.0f / 71.0f);
        const float iy = ys * (float)(H - 1);
        const float fy = floorf(iy);
        sWy[tid] = iy - fy;
        int iy0 = (int)fy; iy0 = iy0 < 0 ? 0 : (iy0 > H - 1 ? H - 1 : iy0);
        const int iy1 = (iy0 + 1 > H - 1) ? H - 1 : iy0 + 1;
        sIy0W[tid] = iy0 * W;
        sIy1W[tid] = iy1 * W;
        sGate[tid] = 1.0f / (1.0f + __expf(-lw[tid]));
    }
    __syncthreads();

    const float* fbase = feat + (size_t)(b * Cq + c0) * (H * W);
    const float* xp    = xsrc + (size_t)xstride * b;
    unsigned short* pb = pooled + (size_t)bl * FRAG_PER_B;
    const int ks   = cg >> 2;
    const int lofs = 16 * (cg & 3);

    // build table for this o-chunk (coalesced row reads)
    constexpr int TOT = 8 * OCH * W;
    for (int idx = tid; idx < TOT; idx += 256) {
        const int row = idx / W;          // c*8 + ol
        const int x   = idx - row * W;
        const int c   = row >> 3;
        const int ol  = row & 7;
        const int o   = oc * OCH + ol;
        const float wy = sWy[o];
        const float* f = fbase + c * (H * W);
        const float v = (1.0f - wy) * f[sIy0W[o] + x] + wy * f[sIy1W[o] + x];
        sT[row * Wp + x] = v * sGate[o];
    }
    __syncthreads();
    if (tid < 8 * OCH) sT[tid * Wp + W] = sT[tid * Wp + W - 1];
    __syncthreads();

    // gather + fragment store: 192 n x 8 o = 1536 points, 6 per thread
    #pragma unroll
    for (int i = 0; i < 6; ++i) {
        const int ptl = i * 256 + tid;
        const int n   = ptl >> 3;
        const int ol  = ptl & 7;
        const int o   = oc * OCH + ol;
        const int pt  = n * NOq + o;
        float ixf = xp[pt] * (float)(W - 1);
        ixf = fminf(fmaxf(ixf, 0.0f), (float)(W - 1));
        const float fx = floorf(ixf);
        const float wx = ixf - fx;
        const int ix0 = (int)fx;
        union { unsigned short u[8]; short8 v; } pk;
        #pragma unroll
        for (int c = 0; c < 8; ++c) {
            const float a0 = sT[(c * OCH + ol) * Wp + ix0];
            const float a1 = sT[(c * OCH + ol) * Wp + ix0 + 1];
            pk.u[c] = f2bf(a0 + wx * (a1 - a0));
        }
        const int nt = pt >> 4;
        const int l  = (pt & 15) + lofs;
        *(short8*)(pb + ((((size_t)nt * 2 + ks) * 64 + l) << 3)) = pk.v;
    }
}

// ---------------------------------------------------------------------------
// Phase 2: MFMA pool.  Block = (b, group of 8 n); each wave owns an n-pair
// (144 pts = 9 tiles).  W-frags in VGPRs; pooled frags straight from global.
// No LDS.  Epilogue: relu -> pairmax -> mean/36 -> accumulate sumFeat.
// ---------------------------------------------------------------------------
__global__ __launch_bounds__(256) void mfma_pool_kernel(
    const unsigned short* __restrict__ pooled,
    const float* __restrict__ lsgi,    // [64][64] this stage
    float* __restrict__ sumFeat,       // [B*NP][64]
    const int b0, const int accumulate)
{
    const int tid  = threadIdx.x;
    const int w    = tid >> 6;
    const int lane = tid & 63;
    const int bl    = blockIdx.x / 24;
    const int ng    = blockIdx.x - bl * 24;
    const int npair = ng * 4 + w;      // 0..95
    const int b     = b0 + bl;

    // build W B-frags: wf[dt][ks], lane holds B[k=ks*32+(lane>>4)*8+j][n=dt*16+(lane&15)]
    short8 wf[4][2];
    {
        const int kb = ((lane >> 4) & 3) * 8;
        const int dl = lane & 15;
        #pragma unroll
        for (int ks = 0; ks < 2; ++ks)
            #pragma unroll
            for (int dt = 0; dt < 4; ++dt) {
                union { unsigned short u[8]; short8 v; } pk;
                #pragma unroll
                for (int j = 0; j < 8; ++j)
                    pk.u[j] = f2bf(lsgi[(ks * 32 + kb + j) * 64 + dt * 16 + dl]);
                wf[dt][ks] = pk.v;
            }
    }

    const unsigned short* pbase = pooled + (size_t)bl * FRAG_PER_B;
    const int nt0 = npair * 9;

    float sums0[4] = {0.f, 0.f, 0.f, 0.f};
    float sums1[4] = {0.f, 0.f, 0.f, 0.f};

    #pragma unroll
    for (int ntl = 0; ntl < 9; ++ntl) {
        const size_t fbase = (((size_t)(nt0 + ntl) * 2) * 64 + lane) << 3;
        const short8 a0 = *(const short8*)(pbase + fbase);
        const short8 a1 = *(const short8*)(pbase + fbase + 512);
        const bool hi = (ntl * 16 + ((lane >> 4) * 4)) >= NOq;
        #pragma unroll
        for (int dt = 0; dt < 4; ++dt) {
            float4v c = {0.f, 0.f, 0.f, 0.f};
            c = __builtin_amdgcn_mfma_f32_16x16x32_bf16(a0, wf[dt][0], c, 0, 0, 0);
            c = __builtin_amdgcn_mfma_f32_16x16x32_bf16(a1, wf[dt][1], c, 0, 0, 0);
            const float pm0 = fmaxf(fmaxf(c[0], c[1]), 0.f);
            const float pm1 = fmaxf(fmaxf(c[2], c[3]), 0.f);
            const float add = pm0 + pm1;
            if (hi) sums1[dt] += add; else sums0[dt] += add;
        }
    }

    // reduce over the 4 quad-lanes
    #pragma unroll
    for (int dt = 0; dt < 4; ++dt) {
        float v0 = sums0[dt], v1 = sums1[dt];
        v0 += __shfl_xor(v0, 16); v0 += __shfl_xor(v0, 32);
        v1 += __shfl_xor(v1, 16); v1 += __shfl_xor(v1, 32);
        sums0[dt] = v0; sums1[dt] = v1;
    }

    if (lane < 16) {
        const size_t row0 = (size_t)(b * NPq + npair * 2) * 64;
        #pragma unroll
        for (int dt = 0; dt < 4; ++dt) {
            const int d = dt * 16 + lane;
            float t0 = sums0[dt] * (1.0f / 36.0f);
            float t1 = sums1[dt] * (1.0f / 36.0f);
            float* p0 = sumFeat + row0 + d;
            float* p1 = sumFeat + row0 + 64 + d;
            if (accumulate) { t0 += *p0; t1 += *p1; }
            *p0 = t0; *p1 = t1;
        }
    }
}

// ---------------------------------------------------------------------------
// Phase 3: heads.  4 waves/block, 4 points/wave (weight loads reused x4).
// ---------------------------------------------------------------------------
__global__ __launch_bounds__(256) void head_kernel(
    const float* __restrict__ sumFeat, const float invS,
    const float* __restrict__ fc_w,  const float* __restrict__ fc_b,
    const float* __restrict__ cls_w, const float* __restrict__ cls_b,
    const float* __restrict__ cls_ow, const float* __restrict__ cls_ob,
    const float* __restrict__ reg_w, const float* __restrict__ reg_b,
    const float* __restrict__ reg_ow, const float* __restrict__ reg_ob,
    const float* __restrict__ loc_w, const float* __restrict__ loc_b,
    const float* __restrict__ loc_ow, const float* __restrict__ loc_ob,
    float* __restrict__ out, float* __restrict__ xs_next)
{
    const int w    = threadIdx.x >> 6;
    const int lane = threadIdx.x & 63;
    const int r0   = w * 4;                       // this wave's LDS rows
    const int p0   = blockIdx.x * 16 + r0;        // global point base

    __shared__ float sFC[16][64];
    __shared__ float sT[16][64];

    float y[4];

    // fused -> sT
    #pragma unroll
    for (int p = 0; p < 4; ++p)
        sT[r0 + p][lane] = sumFeat[(size_t)(p0 + p) * 64 + lane] * invS;
    __syncthreads();

    // fc -> sFC
    y[0] = y[1] = y[2] = y[3] = fc_b[lane];
    for (int c = 0; c < 64; ++c) {
        const float wv = fc_w[c * 64 + lane];
        #pragma unroll
        for (int p = 0; p < 4; ++p) y[p] += sT[r0 + p][c] * wv;
    }
    __syncthreads();
    #pragma unroll
    for (int p = 0; p < 4; ++p) sFC[r0 + p][lane] = fmaxf(y[p], 0.f);
    __syncthreads();

    // ---------------- cls ----------------
    y[0] = y[1] = y[2] = y[3] = cls_b[lane];
    for (int c = 0; c < 64; ++c) {
        const float wv = cls_w[c * 64 + lane];
        #pragma unroll
        for (int p = 0; p < 4; ++p) y[p] += sFC[r0 + p][c] * wv;
    }
    __syncthreads();
    #pragma unroll
    for (int p = 0; p < 4; ++p) sT[r0 + p][lane] = fmaxf(y[p], 0.f);
    __syncthreads();
    y[0] = y[1] = y[2] = y[3] = cls_b[64 + lane];
    for (int c = 0; c < 64; ++c) {
        const float wv = cls_w[4096 + c * 64 + lane];
        #pragma unroll
        for (int p = 0; p < 4; ++p) y[p] += sT[r0 + p][c] * wv;
    }
    __syncthreads();
    #pragma unroll
    for (int p = 0; p < 4; ++p) sT[r0 + p][lane] = fmaxf(y[p], 0.f);
    __syncthreads();
    if (lane < 8) {
        const int p = lane >> 1, d = lane & 1;
        float z = cls_ob[d];
        for (int k = 0; k < 64; ++k) z += sT[r0 + p][k] * cls_ow[k * 2 + d];
        out[(size_t)(p0 + p) * OUTD + d] = z;
    }
    __syncthreads();

    // ---------------- reg ----------------
    y[0] = y[1] = y[2] = y[3] = reg_b[lane];
    for (int c = 0; c < 64; ++c) {
        const float wv = reg_w[c * 64 + lane];
        #pragma unroll
        for (int p = 0; p < 4; ++p) y[p] += sFC[r0 + p][c] * wv;
    }
    __syncthreads();
    #pragma unroll
    for (int p = 0; p < 4; ++p) sT[r0 + p][lane] = fmaxf(y[p], 0.f);
    __syncthreads();
    y[0] = y[1] = y[2] = y[3] = reg_b[64 + lane];
    for (int c = 0; c < 64; ++c) {
        const float wv = reg_w[4096 + c * 64 + lane];
        #pragma unroll
        for (int p = 0; p < 4; ++p) y[p] += sT[r0 + p][c] * wv;
    }
    __syncthreads();
    #pragma unroll
    for (int p = 0; p < 4; ++p) sT[r0 + p][lane] = fmaxf(y[p], 0.f);
    __syncthreads();
    {
        const bool g2 = lane < (REGD - 64);     // lane < 12
        const int j0 = lane;
        const int j1 = 64 + (g2 ? lane : 0);
        #pragma unroll
        for (int p = 0; p < 4; ++p) {
            float z0 = reg_ob[j0];
            float z1 = g2 ? reg_ob[j1] : 0.f;
            for (int k = 0; k < 64; ++k) {
                const float av = sT[r0 + p][k];
                z0 += av * reg_ow[k * REGD + j0];
                if (g2) z1 += av * reg_ow[k * REGD + j1];
            }
            float* orow = out + (size_t)(p0 + p) * OUTD;
            float* xsp  = xs_next + (size_t)(p0 + p) * NOq;
            orow[2 + j0] = z0;
            if (j0 >= 4) xsp[j0 - 4] = 1.0f / (1.0f + __expf(-z0));
            if (g2) {
                orow[2 + j1] = z1;
                xsp[j1 - 4] = 1.0f / (1.0f + __expf(-z1));
            }
        }
    }
    __syncthreads();

    // ---------------- loc ----------------
    y[0] = y[1] = y[2] = y[3] = loc_b[lane];
    for (int c = 0; c < 64; ++c) {
        const float wv = loc_w[c * 64 + lane];
        #pragma unroll
        for (int p = 0; p < 4; ++p) y[p] += sFC[r0 + p][c] * wv;
    }
    __syncthreads();
    #pragma unroll
    for (int p = 0; p < 4; ++p) sT[r0 + p][lane] = fmaxf(y[p], 0.f);
    __syncthreads();
    y[0] = y[1] = y[2] = y[3] = loc_b[64 + lane];
    for (int c = 0; c < 64; ++c) {
        const float wv = loc_w[4096 + c * 64 + lane];
        #pragma unroll
        for (int p = 0; p < 4; ++p) y[p] += sT[r0 + p][c] * wv;
    }
    __syncthreads();
    #pragma unroll
    for (int p = 0; p < 4; ++p) sT[r0 + p][lane] = fmaxf(y[p], 0.f);
    __syncthreads();
    if (lane < 4) {
        const int p = lane;
        float z = loc_ob[0];
        for (int k = 0; k < 64; ++k) z += sT[r0 + p][k] * loc_ow[k];
        out[(size_t)(p0 + p) * OUTD + 78] = z;
    }
}

// ---------------------------------------------------------------------------
extern "C" void kernel_launch(void* const* d_in, const int* in_sizes, int n_in,
                              void* d_out, int out_size, void* d_ws, size_t ws_size,
                              hipStream_t stream)
{
    const float* x0        = (const float*)d_in[0];
    const float* x1        = (const float*)d_in[1];
    const float* x2        = (const float*)d_in[2];
    const float* prior_xs0 = (const float*)d_in[3];
    const float* l_weight  = (const float*)d_in[4];
    const float* lsgi_w    = (const float*)d_in[5];
    const float* fc_w      = (const float*)d_in[6];
    const float* fc_b      = (const float*)d_in[7];
    const float* cls_w     = (const float*)d_in[8];
    const float* cls_b     = (const float*)d_in[9];
    const float* cls_ow    = (const float*)d_in[10];
    const float* cls_ob    = (const float*)d_in[11];
    const float* reg_w     = (const float*)d_in[12];
    const float* reg_b     = (const float*)d_in[13];
    const float* reg_ow    = (const float*)d_in[14];
    const float* reg_ob    = (const float*)d_in[15];
    const float* loc_w     = (const float*)d_in[16];
    const float* loc_b     = (const float*)d_in[17];
    const float* loc_ow    = (const float*)d_in[18];
    const float* loc_ob    = (const float*)d_in[19];

    float* out     = (float*)d_out;
    float* sumFeat = (float*)d_ws;                               // [6144][64] f32
    float* xs      = sumFeat + (size_t)Bq * NPq * Cq;            // [6144][72] f32
    unsigned short* pooled = (unsigned short*)(xs + (size_t)Bq * PTS);

    // batch-chunking so pooled (bf16 frag order) fits in ws
    const size_t fixed_bytes = ((size_t)Bq * NPq * Cq + (size_t)Bq * PTS) * 4;
    const size_t per_b       = FRAG_PER_B * 2;                   // 1.77 MB
    int Bc = Bq;
    if (ws_size < fixed_bytes + (size_t)Bq * per_b) {
        Bc = (int)((ws_size - fixed_bytes) / per_b);
        if (Bc < 1) Bc = 1;
        if (Bc > Bq) Bc = Bq;
    }

    for (int s = 0; s < 3; ++s) {
        const float* xsrc = (s == 0) ? prior_xs0 : xs;
        const int xstr    = (s == 0) ? 0 : PTS;
        for (int c0 = 0; c0 < Bq; c0 += Bc) {
            const int bc = (Bc < Bq - c0) ? Bc : (Bq - c0);
            if (s == 0)
                hipLaunchKernelGGL((rowblend_kernel<10, 25>), dim3(bc * 72), dim3(256), 0, stream,
                                   x2, xsrc, xstr, l_weight, pooled, c0);
            else if (s == 1)
                hipLaunchKernelGGL((rowblend_kernel<20, 50>), dim3(bc * 72), dim3(256), 0, stream,
                                   x1, xsrc, xstr, l_weight, pooled, c0);
            else
                hipLaunchKernelGGL((rowblend_kernel<40, 100>), dim3(bc * 72), dim3(256), 0, stream,
                                   x0, xsrc, xstr, l_weight, pooled, c0);
            hipLaunchKernelGGL(mfma_pool_kernel, dim3(bc * 24), dim3(256), 0, stream,
                               pooled, lsgi_w + s * 4096, sumFeat, c0, (s > 0) ? 1 : 0);
        }
        hipLaunchKernelGGL(head_kernel, dim3(Bq * NPq / 16), dim3(256), 0, stream,
                           sumFeat, 1.0f / (float)(s + 1),
                           fc_w, fc_b, cls_w, cls_b, cls_ow, cls_ob,
                           reg_w, reg_b, reg_ow, reg_ob,
                           loc_w, loc_b, loc_ow, loc_ob,
                           out + (size_t)s * Bq * NPq * OUTD, xs);
    }
}

// Round 5
// 321.983 us; speedup vs baseline: 2.4178x; 1.1205x over previous
//
#include <hip/hip_runtime.h>
#include <hip/hip_bf16.h>

#define Bq   32
#define Cq   64
#define NPq  192
#define NOq  72
#define PTS  (NPq * NOq)   // 13824
#define NTB  (PTS / 16)    // 864 pt-tiles per batch
#define FRAG_PER_B ((size_t)NTB * 2 * 64 * 8)   // ushorts per batch = 884736
#define REGD 76
#define OUTD 79
#define HSTR 68            // padded activation-row stride (words)

typedef __attribute__((ext_vector_type(8))) short short8;
typedef __attribute__((ext_vector_type(4))) float float4v;

__device__ inline unsigned short f2bf(float x) {
    __hip_bfloat16 h = __float2bfloat16(x);
    return *reinterpret_cast<unsigned short*>(&h);
}

// ---------------------------------------------------------------------------
// Phase 1: block = (b, channel-octet, o-chunk-of-8).  Build fp32 gated
// row-blend table in LDS for 8 ch x 8 o, then per point 1-D lerp for the 8
// channels and store one 16-B bf16 fragment chunk (MFMA A-frag order).
// pooled layout: [b][nt][ks][lane][j] bf16,
//   nt=pt>>4, ks=c>>5, lane=(pt&15)+16*((c>>3)&3), j=c&7.
// ---------------------------------------------------------------------------
template<int H, int W>
__global__ __launch_bounds__(256) void rowblend_kernel(
    const float* __restrict__ feat,   // [B][C][H][W]
    const float* __restrict__ xsrc,   // [B][PTS] or [PTS]
    const int xstride,
    const float* __restrict__ lw,     // [72]
    unsigned short* __restrict__ pooled,
    const int b0)
{
    constexpr int Wp  = W + 1;
    constexpr int OCH = 8;
    __shared__ float sT[8 * OCH * Wp];
    __shared__ float sWy[NOq], sGate[NOq];
    __shared__ int   sIy0W[NOq], sIy1W[NOq];

    const int tid = threadIdx.x;
    const int bl  = blockIdx.x / 72;
    const int rem = blockIdx.x - bl * 72;
    const int cg  = rem & 7;           // channel octet
    const int oc  = rem >> 3;          // o-chunk 0..8
    const int b   = b0 + bl;
    const int c0  = cg * 8;

    if (tid < NOq) {
        const float ys = 1.0f - (float)tid * (1.0f / 71.0f);
        const float iy = ys * (float)(H - 1);
        const float fy = floorf(iy);
        sWy[tid] = iy - fy;
        int iy0 = (int)fy; iy0 = iy0 < 0 ? 0 : (iy0 > H - 1 ? H - 1 : iy0);
        const int iy1 = (iy0 + 1 > H - 1) ? H - 1 : iy0 + 1;
        sIy0W[tid] = iy0 * W;
        sIy1W[tid] = iy1 * W;
        sGate[tid] = 1.0f / (1.0f + __expf(-lw[tid]));
    }
    __syncthreads();

    const float* fbase = feat + (size_t)(b * Cq + c0) * (H * W);
    const float* xp    = xsrc + (size_t)xstride * b;
    unsigned short* pb = pooled + (size_t)bl * FRAG_PER_B;
    const int ks   = cg >> 2;
    const int lofs = 16 * (cg & 3);

    // build table for this o-chunk (coalesced row reads)
    constexpr int TOT = 8 * OCH * W;
    for (int idx = tid; idx < TOT; idx += 256) {
        const int row = idx / W;          // c*8 + ol
        const int x   = idx - row * W;
        const int c   = row >> 3;
        const int ol  = row & 7;
        const int o   = oc * OCH + ol;
        const float wy = sWy[o];
        const float* f = fbase + c * (H * W);
        const float v = (1.0f - wy) * f[sIy0W[o] + x] + wy * f[sIy1W[o] + x];
        sT[row * Wp + x] = v * sGate[o];
    }
    __syncthreads();
    if (tid < 8 * OCH) sT[tid * Wp + W] = sT[tid * Wp + W - 1];
    __syncthreads();

    // gather + fragment store: 192 n x 8 o = 1536 points, 6 per thread
    #pragma unroll
    for (int i = 0; i < 6; ++i) {
        const int ptl = i * 256 + tid;
        const int n   = ptl >> 3;
        const int ol  = ptl & 7;
        const int o   = oc * OCH + ol;
        const int pt  = n * NOq + o;
        float ixf = xp[pt] * (float)(W - 1);
        ixf = fminf(fmaxf(ixf, 0.0f), (float)(W - 1));
        const float fx = floorf(ixf);
        const float wx = ixf - fx;
        const int ix0 = (int)fx;
        union { unsigned short u[8]; short8 v; } pk;
        #pragma unroll
        for (int c = 0; c < 8; ++c) {
            const float a0 = sT[(c * OCH + ol) * Wp + ix0];
            const float a1 = sT[(c * OCH + ol) * Wp + ix0 + 1];
            pk.u[c] = f2bf(a0 + wx * (a1 - a0));
        }
        const int nt = pt >> 4;
        const int l  = (pt & 15) + lofs;
        *(short8*)(pb + ((((size_t)nt * 2 + ks) * 64 + l) << 3)) = pk.v;
    }
}

// ---------------------------------------------------------------------------
// Phase 2: MFMA pool.  Block = (b, group of 8 n); each wave owns an n-pair
// (144 pts = 9 tiles).  W-frags in VGPRs; pooled frags straight from global.
// No LDS.  Epilogue: relu -> pairmax -> mean/36 -> accumulate sumFeat.
// ---------------------------------------------------------------------------
__global__ __launch_bounds__(256) void mfma_pool_kernel(
    const unsigned short* __restrict__ pooled,
    const float* __restrict__ lsgi,    // [64][64] this stage
    float* __restrict__ sumFeat,       // [B*NP][64]
    const int b0, const int accumulate)
{
    const int tid  = threadIdx.x;
    const int w    = tid >> 6;
    const int lane = tid & 63;
    const int bl    = blockIdx.x / 24;
    const int ng    = blockIdx.x - bl * 24;
    const int npair = ng * 4 + w;      // 0..95
    const int b     = b0 + bl;

    // build W B-frags: wf[dt][ks], lane holds B[k=ks*32+(lane>>4)*8+j][n=dt*16+(lane&15)]
    short8 wf[4][2];
    {
        const int kb = ((lane >> 4) & 3) * 8;
        const int dl = lane & 15;
        #pragma unroll
        for (int ks = 0; ks < 2; ++ks)
            #pragma unroll
            for (int dt = 0; dt < 4; ++dt) {
                union { unsigned short u[8]; short8 v; } pk;
                #pragma unroll
                for (int j = 0; j < 8; ++j)
                    pk.u[j] = f2bf(lsgi[(ks * 32 + kb + j) * 64 + dt * 16 + dl]);
                wf[dt][ks] = pk.v;
            }
    }

    const unsigned short* pbase = pooled + (size_t)bl * FRAG_PER_B;
    const int nt0 = npair * 9;

    float sums0[4] = {0.f, 0.f, 0.f, 0.f};
    float sums1[4] = {0.f, 0.f, 0.f, 0.f};

    #pragma unroll
    for (int ntl = 0; ntl < 9; ++ntl) {
        const size_t fbase = (((size_t)(nt0 + ntl) * 2) * 64 + lane) << 3;
        const short8 a0 = *(const short8*)(pbase + fbase);
        const short8 a1 = *(const short8*)(pbase + fbase + 512);
        const bool hi = (ntl * 16 + ((lane >> 4) * 4)) >= NOq;
        #pragma unroll
        for (int dt = 0; dt < 4; ++dt) {
            float4v c = {0.f, 0.f, 0.f, 0.f};
            c = __builtin_amdgcn_mfma_f32_16x16x32_bf16(a0, wf[dt][0], c, 0, 0, 0);
            c = __builtin_amdgcn_mfma_f32_16x16x32_bf16(a1, wf[dt][1], c, 0, 0, 0);
            const float pm0 = fmaxf(fmaxf(c[0], c[1]), 0.f);
            const float pm1 = fmaxf(fmaxf(c[2], c[3]), 0.f);
            const float add = pm0 + pm1;
            if (hi) sums1[dt] += add; else sums0[dt] += add;
        }
    }

    // reduce over the 4 quad-lanes
    #pragma unroll
    for (int dt = 0; dt < 4; ++dt) {
        float v0 = sums0[dt], v1 = sums1[dt];
        v0 += __shfl_xor(v0, 16); v0 += __shfl_xor(v0, 32);
        v1 += __shfl_xor(v1, 16); v1 += __shfl_xor(v1, 32);
        sums0[dt] = v0; sums1[dt] = v1;
    }

    if (lane < 16) {
        const size_t row0 = (size_t)(b * NPq + npair * 2) * 64;
        #pragma unroll
        for (int dt = 0; dt < 4; ++dt) {
            const int d = dt * 16 + lane;
            float t0 = sums0[dt] * (1.0f / 36.0f);
            float t1 = sums1[dt] * (1.0f / 36.0f);
            float* p0 = sumFeat + row0 + d;
            float* p1 = sumFeat + row0 + 64 + d;
            if (accumulate) { t0 += *p0; t1 += *p1; }
            *p0 = t0; *p1 = t1;
        }
    }
}

// ---------------------------------------------------------------------------
// Phase 3: heads as register-tiled fp32 GEMM chain.  Block = 32 points,
// 256 threads as 16x16 (2 rows x 4 cols per thread).  Per-layer weights
// staged in LDS; float4 operand reads; reg_ow also staged in LDS.
// ---------------------------------------------------------------------------
__global__ __launch_bounds__(256) void head_kernel(
    const float* __restrict__ sumFeat, const float invS,
    const float* __restrict__ fc_w,  const float* __restrict__ fc_b,
    const float* __restrict__ cls_w, const float* __restrict__ cls_b,
    const float* __restrict__ cls_ow, const float* __restrict__ cls_ob,
    const float* __restrict__ reg_w, const float* __restrict__ reg_b,
    const float* __restrict__ reg_ow, const float* __restrict__ reg_ob,
    const float* __restrict__ loc_w, const float* __restrict__ loc_b,
    const float* __restrict__ loc_ow, const float* __restrict__ loc_ob,
    float* __restrict__ out, float* __restrict__ xs_next)
{
    __shared__ __align__(16) float sFC[32 * HSTR];
    __shared__ __align__(16) float sA[32 * HSTR];
    __shared__ __align__(16) float sB[32 * HSTR];
    __shared__ __align__(16) float sW[64 * REGD];   // holds 64x64 layers or reg_ow

    const int tid = threadIdx.x;
    const int p0  = blockIdx.x * 32;
    const int tm  = tid >> 4;     // 0..15 -> rows 2tm, 2tm+1
    const int tn  = tid & 15;     // cols 4tn..4tn+3

    // load fused = sumFeat * invS into sA
    for (int idx = tid; idx < 32 * 64; idx += 256) {
        const int p = idx >> 6, c = idx & 63;
        sA[p * HSTR + c] = sumFeat[(size_t)(p0 + p) * 64 + c] * invS;
    }

    auto do_gemm = [&](const float* __restrict__ gw, const float* __restrict__ gb,
                       const float* src, float* dst) {
        __syncthreads();                               // src ready, sW free
        for (int idx = tid; idx < 4096; idx += 256) sW[idx] = gw[idx];
        __syncthreads();
        const float4 b4 = *(const float4*)&gb[4 * tn];
        float4 acc0 = b4, acc1 = b4;
        const float* r0 = src + (2 * tm) * HSTR;
        const float* r1 = r0 + HSTR;
        #pragma unroll 4
        for (int k4 = 0; k4 < 16; ++k4) {
            const float4 a0 = *(const float4*)&r0[4 * k4];
            const float4 a1 = *(const float4*)&r1[4 * k4];
            const float4 w0 = *(const float4*)&sW[(4 * k4 + 0) * 64 + 4 * tn];
            const float4 w1 = *(const float4*)&sW[(4 * k4 + 1) * 64 + 4 * tn];
            const float4 w2 = *(const float4*)&sW[(4 * k4 + 2) * 64 + 4 * tn];
            const float4 w3 = *(const float4*)&sW[(4 * k4 + 3) * 64 + 4 * tn];
            acc0.x += a0.x*w0.x + a0.y*w1.x + a0.z*w2.x + a0.w*w3.x;
            acc0.y += a0.x*w0.y + a0.y*w1.y + a0.z*w2.y + a0.w*w3.y;
            acc0.z += a0.x*w0.z + a0.y*w1.z + a0.z*w2.z + a0.w*w3.z;
            acc0.w += a0.x*w0.w + a0.y*w1.w + a0.z*w2.w + a0.w*w3.w;
            acc1.x += a1.x*w0.x + a1.y*w1.x + a1.z*w2.x + a1.w*w3.x;
            acc1.y += a1.x*w0.y + a1.y*w1.y + a1.z*w2.y + a1.w*w3.y;
            acc1.z += a1.x*w0.z + a1.y*w1.z + a1.z*w2.z + a1.w*w3.z;
            acc1.w += a1.x*w0.w + a1.y*w1.w + a1.z*w2.w + a1.w*w3.w;
        }
        float4 v0, v1;
        v0.x = fmaxf(acc0.x, 0.f); v0.y = fmaxf(acc0.y, 0.f);
        v0.z = fmaxf(acc0.z, 0.f); v0.w = fmaxf(acc0.w, 0.f);
        v1.x = fmaxf(acc1.x, 0.f); v1.y = fmaxf(acc1.y, 0.f);
        v1.z = fmaxf(acc1.z, 0.f); v1.w = fmaxf(acc1.w, 0.f);
        *(float4*)&dst[(2 * tm) * HSTR + 4 * tn]     = v0;
        *(float4*)&dst[(2 * tm + 1) * HSTR + 4 * tn] = v1;
    };

    do_gemm(fc_w, fc_b, sA, sFC);

    // ---------------- cls ----------------
    do_gemm(cls_w,        cls_b,      sFC, sA);
    do_gemm(cls_w + 4096, cls_b + 64, sA,  sB);
    __syncthreads();
    if (tid < 64) {
        const int p = tid >> 1, d = tid & 1;
        const float* row = &sB[p * HSTR];
        float z = cls_ob[d];
        #pragma unroll 4
        for (int k4 = 0; k4 < 16; ++k4) {
            const float4 a = *(const float4*)&row[4 * k4];
            z += a.x * cls_ow[(4 * k4 + 0) * 2 + d] + a.y * cls_ow[(4 * k4 + 1) * 2 + d]
               + a.z * cls_ow[(4 * k4 + 2) * 2 + d] + a.w * cls_ow[(4 * k4 + 3) * 2 + d];
        }
        out[(size_t)(p0 + p) * OUTD + d] = z;
    }

    // ---------------- reg ----------------
    do_gemm(reg_w,        reg_b,      sFC, sA);
    do_gemm(reg_w + 4096, reg_b + 64, sA,  sB);
    __syncthreads();                                   // sW reads done
    for (int idx = tid; idx < 64 * REGD; idx += 256) sW[idx] = reg_ow[idx];
    __syncthreads();
    {
        const int p  = tid & 31;
        const int jg = tid >> 5;                       // 0..7
        const float* row = &sB[p * HSTR];
        float* orow = out + (size_t)(p0 + p) * OUTD;
        float* xsp  = xs_next + (size_t)(p0 + p) * NOq;
        for (int j = jg; j < REGD; j += 8) {
            float z = reg_ob[j];
            #pragma unroll 4
            for (int k4 = 0; k4 < 16; ++k4) {
                const float4 a = *(const float4*)&row[4 * k4];
                z += a.x * sW[(4 * k4 + 0) * REGD + j] + a.y * sW[(4 * k4 + 1) * REGD + j]
                   + a.z * sW[(4 * k4 + 2) * REGD + j] + a.w * sW[(4 * k4 + 3) * REGD + j];
            }
            orow[2 + j] = z;
            if (j >= 4) xsp[j - 4] = 1.0f / (1.0f + __expf(-z));
        }
    }

    // ---------------- loc ----------------
    do_gemm(loc_w,        loc_b,      sFC, sA);
    do_gemm(loc_w + 4096, loc_b + 64, sA,  sB);
    __syncthreads();
    if (tid < 32) {
        const float* row = &sB[tid * HSTR];
        float z = loc_ob[0];
        #pragma unroll 4
        for (int k4 = 0; k4 < 16; ++k4) {
            const float4 a = *(const float4*)&row[4 * k4];
            z += a.x * loc_ow[4 * k4] + a.y * loc_ow[4 * k4 + 1]
               + a.z * loc_ow[4 * k4 + 2] + a.w * loc_ow[4 * k4 + 3];
        }
        out[(size_t)(p0 + tid) * OUTD + 78] = z;
    }
}

// ---------------------------------------------------------------------------
extern "C" void kernel_launch(void* const* d_in, const int* in_sizes, int n_in,
                              void* d_out, int out_size, void* d_ws, size_t ws_size,
                              hipStream_t stream)
{
    const float* x0        = (const float*)d_in[0];
    const float* x1        = (const float*)d_in[1];
    const float* x2        = (const float*)d_in[2];
    const float* prior_xs0 = (const float*)d_in[3];
    const float* l_weight  = (const float*)d_in[4];
    const float* lsgi_w    = (const float*)d_in[5];
    const float* fc_w      = (const float*)d_in[6];
    const float* fc_b      = (const float*)d_in[7];
    const float* cls_w     = (const float*)d_in[8];
    const float* cls_b     = (const float*)d_in[9];
    const float* cls_ow    = (const float*)d_in[10];
    const float* cls_ob    = (const float*)d_in[11];
    const float* reg_w     = (const float*)d_in[12];
    const float* reg_b     = (const float*)d_in[13];
    const float* reg_ow    = (const float*)d_in[14];
    const float* reg_ob    = (const float*)d_in[15];
    const float* loc_w     = (const float*)d_in[16];
    const float* loc_b     = (const float*)d_in[17];
    const float* loc_ow    = (const float*)d_in[18];
    const float* loc_ob    = (const float*)d_in[19];

    float* out     = (float*)d_out;
    float* sumFeat = (float*)d_ws;                               // [6144][64] f32
    float* xs      = sumFeat + (size_t)Bq * NPq * Cq;            // [6144][72] f32
    unsigned short* pooled = (unsigned short*)(xs + (size_t)Bq * PTS);

    // batch-chunking so pooled (bf16 frag order) fits in ws
    const size_t fixed_bytes = ((size_t)Bq * NPq * Cq + (size_t)Bq * PTS) * 4;
    const size_t per_b       = FRAG_PER_B * 2;                   // 1.77 MB
    int Bc = Bq;
    if (ws_size < fixed_bytes + (size_t)Bq * per_b) {
        Bc = (int)((ws_size - fixed_bytes) / per_b);
        if (Bc < 1) Bc = 1;
        if (Bc > Bq) Bc = Bq;
    }

    for (int s = 0; s < 3; ++s) {
        const float* xsrc = (s == 0) ? prior_xs0 : xs;
        const int xstr    = (s == 0) ? 0 : PTS;
        for (int c0 = 0; c0 < Bq; c0 += Bc) {
            const int bc = (Bc < Bq - c0) ? Bc : (Bq - c0);
            if (s == 0)
                hipLaunchKernelGGL((rowblend_kernel<10, 25>), dim3(bc * 72), dim3(256), 0, stream,
                                   x2, xsrc, xstr, l_weight, pooled, c0);
            else if (s == 1)
                hipLaunchKernelGGL((rowblend_kernel<20, 50>), dim3(bc * 72), dim3(256), 0, stream,
                                   x1, xsrc, xstr, l_weight, pooled, c0);
            else
                hipLaunchKernelGGL((rowblend_kernel<40, 100>), dim3(bc * 72), dim3(256), 0, stream,
                                   x0, xsrc, xstr, l_weight, pooled, c0);
            hipLaunchKernelGGL(mfma_pool_kernel, dim3(bc * 24), dim3(256), 0, stream,
                               pooled, lsgi_w + s * 4096, sumFeat, c0, (s > 0) ? 1 : 0);
        }
        hipLaunchKernelGGL(head_kernel, dim3(Bq * NPq / 32), dim3(256), 0, stream,
                           sumFeat, 1.0f / (float)(s + 1),
                           fc_w, fc_b, cls_w, cls_b, cls_ow, cls_ob,
                           reg_w, reg_b, reg_ow, reg_ob,
                           loc_w, loc_b, loc_ow, loc_ob,
                           out + (size_t)s * Bq * NPq * OUTD, xs);
    }
}

// Round 6
// 282.721 us; speedup vs baseline: 2.7536x; 1.1389x over previous
//
#include <hip/hip_runtime.h>
#include <hip/hip_bf16.h>

#define Bq   32
#define Cq   64
#define NPq  192
#define NOq  72
#define PTS  (NPq * NOq)   // 13824
#define NTB  (PTS / 16)    // 864 pt-tiles per batch
#define FRAG_PER_B ((size_t)NTB * 2 * 64 * 8)   // ushorts per batch = 884736
#define REGD 76
#define OUTD 79
#define HSTR 68            // padded activation-row stride (words)

typedef __attribute__((ext_vector_type(8))) short short8;
typedef __attribute__((ext_vector_type(4))) float float4v;

__device__ inline unsigned short f2bf(float x) {
    __hip_bfloat16 h = __float2bfloat16(x);
    return *reinterpret_cast<unsigned short*>(&h);
}

// ---------------------------------------------------------------------------
// Phase 1: block = (b, channel-octet, o-chunk-of-8).  Build fp32 gated
// row-blend table in LDS for 8 ch x 8 o, then per point 1-D lerp for the 8
// channels and store one 16-B bf16 fragment chunk (MFMA A-frag order).
// pooled layout: [b][nt][ks][lane][j] bf16,
//   nt=pt>>4, ks=c>>5, lane=(pt&15)+16*((c>>3)&3), j=c&7.
// ---------------------------------------------------------------------------
template<int H, int W>
__global__ __launch_bounds__(256) void rowblend_kernel(
    const float* __restrict__ feat,   // [B][C][H][W]
    const float* __restrict__ xsrc,   // [B][PTS] or [PTS]
    const int xstride,
    const float* __restrict__ lw,     // [72]
    unsigned short* __restrict__ pooled,
    const int b0)
{
    constexpr int Wp  = W + 1;
    constexpr int OCH = 8;
    __shared__ float sT[8 * OCH * Wp];
    __shared__ float sWy[NOq], sGate[NOq];
    __shared__ int   sIy0W[NOq], sIy1W[NOq];

    const int tid = threadIdx.x;
    const int bl  = blockIdx.x / 72;
    const int rem = blockIdx.x - bl * 72;
    const int cg  = rem & 7;           // channel octet
    const int oc  = rem >> 3;          // o-chunk 0..8
    const int b   = b0 + bl;
    const int c0  = cg * 8;

    if (tid < NOq) {
        const float ys = 1.0f - (float)tid * (1.0f / 71.0f);
        const float iy = ys * (float)(H - 1);
        const float fy = floorf(iy);
        sWy[tid] = iy - fy;
        int iy0 = (int)fy; iy0 = iy0 < 0 ? 0 : (iy0 > H - 1 ? H - 1 : iy0);
        const int iy1 = (iy0 + 1 > H - 1) ? H - 1 : iy0 + 1;
        sIy0W[tid] = iy0 * W;
        sIy1W[tid] = iy1 * W;
        sGate[tid] = 1.0f / (1.0f + __expf(-lw[tid]));
    }
    __syncthreads();

    const float* fbase = feat + (size_t)(b * Cq + c0) * (H * W);
    const float* xp    = xsrc + (size_t)xstride * b;
    unsigned short* pb = pooled + (size_t)bl * FRAG_PER_B;
    const int ks   = cg >> 2;
    const int lofs = 16 * (cg & 3);

    // build table for this o-chunk (coalesced row reads)
    constexpr int TOT = 8 * OCH * W;
    for (int idx = tid; idx < TOT; idx += 256) {
        const int row = idx / W;          // c*8 + ol
        const int x   = idx - row * W;
        const int c   = row >> 3;
        const int ol  = row & 7;
        const int o   = oc * OCH + ol;
        const float wy = sWy[o];
        const float* f = fbase + c * (H * W);
        const float v = (1.0f - wy) * f[sIy0W[o] + x] + wy * f[sIy1W[o] + x];
        sT[row * Wp + x] = v * sGate[o];
    }
    __syncthreads();
    if (tid < 8 * OCH) sT[tid * Wp + W] = sT[tid * Wp + W - 1];
    __syncthreads();

    // gather + fragment store: 192 n x 8 o = 1536 points, 6 per thread
    #pragma unroll
    for (int i = 0; i < 6; ++i) {
        const int ptl = i * 256 + tid;
        const int n   = ptl >> 3;
        const int ol  = ptl & 7;
        const int o   = oc * OCH + ol;
        const int pt  = n * NOq + o;
        float ixf = xp[pt] * (float)(W - 1);
        ixf = fminf(fmaxf(ixf, 0.0f), (float)(W - 1));
        const float fx = floorf(ixf);
        const float wx = ixf - fx;
        const int ix0 = (int)fx;
        union { unsigned short u[8]; short8 v; } pk;
        #pragma unroll
        for (int c = 0; c < 8; ++c) {
            const float a0 = sT[(c * OCH + ol) * Wp + ix0];
            const float a1 = sT[(c * OCH + ol) * Wp + ix0 + 1];
            pk.u[c] = f2bf(a0 + wx * (a1 - a0));
        }
        const int nt = pt >> 4;
        const int l  = (pt & 15) + lofs;
        *(short8*)(pb + ((((size_t)nt * 2 + ks) * 64 + l) << 3)) = pk.v;
    }
}

// ---------------------------------------------------------------------------
// Phase 2: MFMA pool.  Block = (b, group of 8 n); each wave owns an n-pair
// (144 pts = 9 tiles).  W-frags in VGPRs; pooled frags straight from global.
// No LDS.  Epilogue: relu -> pairmax -> mean/36 -> accumulate sumFeat.
// ---------------------------------------------------------------------------
__global__ __launch_bounds__(256) void mfma_pool_kernel(
    const unsigned short* __restrict__ pooled,
    const float* __restrict__ lsgi,    // [64][64] this stage
    float* __restrict__ sumFeat,       // [B*NP][64]
    const int b0, const int accumulate)
{
    const int tid  = threadIdx.x;
    const int w    = tid >> 6;
    const int lane = tid & 63;
    const int bl    = blockIdx.x / 24;
    const int ng    = blockIdx.x - bl * 24;
    const int npair = ng * 4 + w;      // 0..95
    const int b     = b0 + bl;

    // build W B-frags: wf[dt][ks], lane holds B[k=ks*32+(lane>>4)*8+j][n=dt*16+(lane&15)]
    short8 wf[4][2];
    {
        const int kb = ((lane >> 4) & 3) * 8;
        const int dl = lane & 15;
        #pragma unroll
        for (int ks = 0; ks < 2; ++ks)
            #pragma unroll
            for (int dt = 0; dt < 4; ++dt) {
                union { unsigned short u[8]; short8 v; } pk;
                #pragma unroll
                for (int j = 0; j < 8; ++j)
                    pk.u[j] = f2bf(lsgi[(ks * 32 + kb + j) * 64 + dt * 16 + dl]);
                wf[dt][ks] = pk.v;
            }
    }

    const unsigned short* pbase = pooled + (size_t)bl * FRAG_PER_B;
    const int nt0 = npair * 9;

    float sums0[4] = {0.f, 0.f, 0.f, 0.f};
    float sums1[4] = {0.f, 0.f, 0.f, 0.f};

    #pragma unroll
    for (int ntl = 0; ntl < 9; ++ntl) {
        const size_t fbase = (((size_t)(nt0 + ntl) * 2) * 64 + lane) << 3;
        const short8 a0 = *(const short8*)(pbase + fbase);
        const short8 a1 = *(const short8*)(pbase + fbase + 512);
        const bool hi = (ntl * 16 + ((lane >> 4) * 4)) >= NOq;
        #pragma unroll
        for (int dt = 0; dt < 4; ++dt) {
            float4v c = {0.f, 0.f, 0.f, 0.f};
            c = __builtin_amdgcn_mfma_f32_16x16x32_bf16(a0, wf[dt][0], c, 0, 0, 0);
            c = __builtin_amdgcn_mfma_f32_16x16x32_bf16(a1, wf[dt][1], c, 0, 0, 0);
            const float pm0 = fmaxf(fmaxf(c[0], c[1]), 0.f);
            const float pm1 = fmaxf(fmaxf(c[2], c[3]), 0.f);
            const float add = pm0 + pm1;
            if (hi) sums1[dt] += add; else sums0[dt] += add;
        }
    }

    // reduce over the 4 quad-lanes
    #pragma unroll
    for (int dt = 0; dt < 4; ++dt) {
        float v0 = sums0[dt], v1 = sums1[dt];
        v0 += __shfl_xor(v0, 16); v0 += __shfl_xor(v0, 32);
        v1 += __shfl_xor(v1, 16); v1 += __shfl_xor(v1, 32);
        sums0[dt] = v0; sums1[dt] = v1;
    }

    if (lane < 16) {
        const size_t row0 = (size_t)(b * NPq + npair * 2) * 64;
        #pragma unroll
        for (int dt = 0; dt < 4; ++dt) {
            const int d = dt * 16 + lane;
            float t0 = sums0[dt] * (1.0f / 36.0f);
            float t1 = sums1[dt] * (1.0f / 36.0f);
            float* p0 = sumFeat + row0 + d;
            float* p1 = sumFeat + row0 + 64 + d;
            if (accumulate) { t0 += *p0; t1 += *p1; }
            *p0 = t0; *p1 = t1;
        }
    }
}

// ---------------------------------------------------------------------------
// Phase 3: heads.  Block = (point-group of 32, head-branch).  Grid 192*3.
// Each block: fc -> h1 -> h2 -> projection for ONE branch (fc recomputed per
// branch for 3x parallelism).  Weight staging software-pipelined: next
// layer's weights load to regs during current GEMM, stored to the alternate
// LDS buffer after.  fp32 throughout.
// ---------------------------------------------------------------------------
__global__ __launch_bounds__(256) void head_kernel(
    const float* __restrict__ sumFeat, const float invS,
    const float* __restrict__ fc_w,  const float* __restrict__ fc_b,
    const float* __restrict__ cls_w, const float* __restrict__ cls_b,
    const float* __restrict__ cls_ow, const float* __restrict__ cls_ob,
    const float* __restrict__ reg_w, const float* __restrict__ reg_b,
    const float* __restrict__ reg_ow, const float* __restrict__ reg_ob,
    const float* __restrict__ loc_w, const float* __restrict__ loc_b,
    const float* __restrict__ loc_ow, const float* __restrict__ loc_ob,
    float* __restrict__ out, float* __restrict__ xs_next)
{
    __shared__ __align__(16) float sAct0[32 * HSTR];
    __shared__ __align__(16) float sAct1[32 * HSTR];
    __shared__ __align__(16) float sW0[4096];
    __shared__ __align__(16) float sW1[4864];   // fits reg_ow (64*76)

    const int tid = threadIdx.x;
    const int hb  = blockIdx.x % 3;            // 0=cls 1=reg 2=loc
    const int pg  = blockIdx.x / 3;
    const int p0  = pg * 32;
    const int tm  = tid >> 4;
    const int tn  = tid & 15;

    const float* h_w  = (hb == 0) ? cls_w  : (hb == 1) ? reg_w  : loc_w;
    const float* h_b  = (hb == 0) ? cls_b  : (hb == 1) ? reg_b  : loc_b;
    const float* h_ow = (hb == 0) ? cls_ow : (hb == 1) ? reg_ow : loc_ow;
    const float* h_ob = (hb == 0) ? cls_ob : (hb == 1) ? reg_ob : loc_ob;
    const int ow_n    = (hb == 0) ? 128    : (hb == 1) ? 64 * REGD : 64;

    // stage fc_w -> sW0 and fused -> sAct0
    #pragma unroll
    for (int i = 0; i < 4; ++i)
        *(float4*)&sW0[(i * 256 + tid) * 4] = *(const float4*)&fc_w[(i * 256 + tid) * 4];
    for (int idx = tid; idx < 32 * 64; idx += 256) {
        const int p = idx >> 6, c = idx & 63;
        sAct0[p * HSTR + c] = sumFeat[(size_t)(p0 + p) * 64 + c] * invS;
    }

    // GEMM with prefetch of next weights (nextn words into regs, stored to
    // nextbuf after compute).
    auto do_gemm = [&](const float* src, float* dst, const float* wbuf,
                       const float* gb, const float* nextw, int nextn,
                       float* nextbuf) {
        __syncthreads();
        float4 pf[5];
        const int n4 = nextn >> 2;
        #pragma unroll
        for (int i = 0; i < 5; ++i) {
            const int idx = i * 256 + tid;
            if (idx < n4) pf[i] = *(const float4*)&nextw[idx * 4];
        }
        const float4 b4 = *(const float4*)&gb[4 * tn];
        float4 acc0 = b4, acc1 = b4;
        const float* r0 = src + (2 * tm) * HSTR;
        const float* r1 = r0 + HSTR;
        #pragma unroll 4
        for (int k4 = 0; k4 < 16; ++k4) {
            const float4 a0 = *(const float4*)&r0[4 * k4];
            const float4 a1 = *(const float4*)&r1[4 * k4];
            const float4 w0 = *(const float4*)&wbuf[(4 * k4 + 0) * 64 + 4 * tn];
            const float4 w1 = *(const float4*)&wbuf[(4 * k4 + 1) * 64 + 4 * tn];
            const float4 w2 = *(const float4*)&wbuf[(4 * k4 + 2) * 64 + 4 * tn];
            const float4 w3 = *(const float4*)&wbuf[(4 * k4 + 3) * 64 + 4 * tn];
            acc0.x += a0.x*w0.x + a0.y*w1.x + a0.z*w2.x + a0.w*w3.x;
            acc0.y += a0.x*w0.y + a0.y*w1.y + a0.z*w2.y + a0.w*w3.y;
            acc0.z += a0.x*w0.z + a0.y*w1.z + a0.z*w2.z + a0.w*w3.z;
            acc0.w += a0.x*w0.w + a0.y*w1.w + a0.z*w2.w + a0.w*w3.w;
            acc1.x += a1.x*w0.x + a1.y*w1.x + a1.z*w2.x + a1.w*w3.x;
            acc1.y += a1.x*w0.y + a1.y*w1.y + a1.z*w2.y + a1.w*w3.y;
            acc1.z += a1.x*w0.z + a1.y*w1.z + a1.z*w2.z + a1.w*w3.z;
            acc1.w += a1.x*w0.w + a1.y*w1.w + a1.z*w2.w + a1.w*w3.w;
        }
        float4 v0, v1;
        v0.x = fmaxf(acc0.x, 0.f); v0.y = fmaxf(acc0.y, 0.f);
        v0.z = fmaxf(acc0.z, 0.f); v0.w = fmaxf(acc0.w, 0.f);
        v1.x = fmaxf(acc1.x, 0.f); v1.y = fmaxf(acc1.y, 0.f);
        v1.z = fmaxf(acc1.z, 0.f); v1.w = fmaxf(acc1.w, 0.f);
        *(float4*)&dst[(2 * tm) * HSTR + 4 * tn]     = v0;
        *(float4*)&dst[(2 * tm + 1) * HSTR + 4 * tn] = v1;
        #pragma unroll
        for (int i = 0; i < 5; ++i) {
            const int idx = i * 256 + tid;
            if (idx < n4) *(float4*)&nextbuf[idx * 4] = pf[i];
        }
    };

    // fc (sW0) -> h1 (sW1) -> h2 (sW0) -> proj (sW1)
    do_gemm(sAct0, sAct1, sW0, fc_b,      h_w,        4096, sW1);
    do_gemm(sAct1, sAct0, sW1, h_b,       h_w + 4096, 4096, sW0);
    do_gemm(sAct0, sAct1, sW0, h_b + 64,  h_ow,       ow_n, sW1);
    __syncthreads();

    // projection from sAct1 using sW1
    if (hb == 0) {                      // cls: 2 outputs
        if (tid < 64) {
            const int p = tid >> 1, d = tid & 1;
            const float* row = &sAct1[p * HSTR];
            float z = h_ob[d];
            #pragma unroll 4
            for (int k4 = 0; k4 < 16; ++k4) {
                const float4 a = *(const float4*)&row[4 * k4];
                z += a.x * sW1[(4 * k4 + 0) * 2 + d] + a.y * sW1[(4 * k4 + 1) * 2 + d]
                   + a.z * sW1[(4 * k4 + 2) * 2 + d] + a.w * sW1[(4 * k4 + 3) * 2 + d];
            }
            out[(size_t)(p0 + p) * OUTD + d] = z;
        }
    } else if (hb == 1) {               // reg: 76 outputs + xs_next
        const int p  = tid & 31;
        const int jg = tid >> 5;
        const float* row = &sAct1[p * HSTR];
        float* orow = out + (size_t)(p0 + p) * OUTD;
        float* xsp  = xs_next + (size_t)(p0 + p) * NOq;
        for (int j = jg; j < REGD; j += 8) {
            float z = h_ob[j];
            #pragma unroll 4
            for (int k4 = 0; k4 < 16; ++k4) {
                const float4 a = *(const float4*)&row[4 * k4];
                z += a.x * sW1[(4 * k4 + 0) * REGD + j] + a.y * sW1[(4 * k4 + 1) * REGD + j]
                   + a.z * sW1[(4 * k4 + 2) * REGD + j] + a.w * sW1[(4 * k4 + 3) * REGD + j];
            }
            orow[2 + j] = z;
            if (j >= 4) xsp[j - 4] = 1.0f / (1.0f + __expf(-z));
        }
    } else {                            // loc: 1 output
        if (tid < 32) {
            const float* row = &sAct1[tid * HSTR];
            float z = h_ob[0];
            #pragma unroll 4
            for (int k4 = 0; k4 < 16; ++k4) {
                const float4 a = *(const float4*)&row[4 * k4];
                z += a.x * sW1[4 * k4] + a.y * sW1[4 * k4 + 1]
                   + a.z * sW1[4 * k4 + 2] + a.w * sW1[4 * k4 + 3];
            }
            out[(size_t)(p0 + tid) * OUTD + 78] = z;
        }
    }
}

// ---------------------------------------------------------------------------
extern "C" void kernel_launch(void* const* d_in, const int* in_sizes, int n_in,
                              void* d_out, int out_size, void* d_ws, size_t ws_size,
                              hipStream_t stream)
{
    const float* x0        = (const float*)d_in[0];
    const float* x1        = (const float*)d_in[1];
    const float* x2        = (const float*)d_in[2];
    const float* prior_xs0 = (const float*)d_in[3];
    const float* l_weight  = (const float*)d_in[4];
    const float* lsgi_w    = (const float*)d_in[5];
    const float* fc_w      = (const float*)d_in[6];
    const float* fc_b      = (const float*)d_in[7];
    const float* cls_w     = (const float*)d_in[8];
    const float* cls_b     = (const float*)d_in[9];
    const float* cls_ow    = (const float*)d_in[10];
    const float* cls_ob    = (const float*)d_in[11];
    const float* reg_w     = (const float*)d_in[12];
    const float* reg_b     = (const float*)d_in[13];
    const float* reg_ow    = (const float*)d_in[14];
    const float* reg_ob    = (const float*)d_in[15];
    const float* loc_w     = (const float*)d_in[16];
    const float* loc_b     = (const float*)d_in[17];
    const float* loc_ow    = (const float*)d_in[18];
    const float* loc_ob    = (const float*)d_in[19];

    float* out     = (float*)d_out;
    float* sumFeat = (float*)d_ws;                               // [6144][64] f32
    float* xs      = sumFeat + (size_t)Bq * NPq * Cq;            // [6144][72] f32
    unsigned short* pooled = (unsigned short*)(xs + (size_t)Bq * PTS);

    // batch-chunking so pooled (bf16 frag order) fits in ws
    const size_t fixed_bytes = ((size_t)Bq * NPq * Cq + (size_t)Bq * PTS) * 4;
    const size_t per_b       = FRAG_PER_B * 2;                   // 1.77 MB
    int Bc = Bq;
    if (ws_size < fixed_bytes + (size_t)Bq * per_b) {
        Bc = (int)((ws_size - fixed_bytes) / per_b);
        if (Bc < 1) Bc = 1;
        if (Bc > Bq) Bc = Bq;
    }

    for (int s = 0; s < 3; ++s) {
        const float* xsrc = (s == 0) ? prior_xs0 : xs;
        const int xstr    = (s == 0) ? 0 : PTS;
        for (int c0 = 0; c0 < Bq; c0 += Bc) {
            const int bc = (Bc < Bq - c0) ? Bc : (Bq - c0);
            if (s == 0)
                hipLaunchKernelGGL((rowblend_kernel<10, 25>), dim3(bc * 72), dim3(256), 0, stream,
                                   x2, xsrc, xstr, l_weight, pooled, c0);
            else if (s == 1)
                hipLaunchKernelGGL((rowblend_kernel<20, 50>), dim3(bc * 72), dim3(256), 0, stream,
                                   x1, xsrc, xstr, l_weight, pooled, c0);
            else
                hipLaunchKernelGGL((rowblend_kernel<40, 100>), dim3(bc * 72), dim3(256), 0, stream,
                                   x0, xsrc, xstr, l_weight, pooled, c0);
            hipLaunchKernelGGL(mfma_pool_kernel, dim3(bc * 24), dim3(256), 0, stream,
                               pooled, lsgi_w + s * 4096, sumFeat, c0, (s > 0) ? 1 : 0);
        }
        hipLaunchKernelGGL(head_kernel, dim3((Bq * NPq / 32) * 3), dim3(256), 0, stream,
                           sumFeat, 1.0f / (float)(s + 1),
                           fc_w, fc_b, cls_w, cls_b, cls_ow, cls_ob,
                           reg_w, reg_b, reg_ow, reg_ob,
                           loc_w, loc_b, loc_ow, loc_ob,
                           out + (size_t)s * Bq * NPq * OUTD, xs);
    }
}